// Round 5
// baseline (447.876 us; speedup 1.0000x reference)
//
#include <hip/hip_runtime.h>
#include <hip/hip_bf16.h>
#include <cstdint>
#include <cstddef>

// TransformerEncoderLayer: B=2 S=2048 D=1024 H=16 DH=64 DFF=4096, fp32 in/out.
// Round 4: 256^2 8-phase counted-vmcnt GEMM (T2+T3+T4+T5) for QKV/FFN1 and,
// via split-K + f32 atomicAdd, FFN2 (z=4) and both convs (z=3 taps).
// Schedule: 8 half-tile slots (2dbuf x 2half x A,B x 16KB); per phase:
// {ds_read frags, stage 1 half-tile, vmcnt(6), barrier, lgkmcnt(0), 16 MFMA
// (setprio-wrapped), barrier}. All stage->first-use leads >= 4 phases.

#define SB 2048
#define DD 1024
#define NB 2
#define NH 16
#define DFF_ 4096
#define NTOK (NB*SB)   // 4096
#define SP (SB+2)      // 2050 (padded rows for conv halo)

typedef unsigned short u16;
typedef unsigned int u32;
typedef float f32x4 __attribute__((ext_vector_type(4)));
typedef float f32x16 __attribute__((ext_vector_type(16)));
typedef short s16x8 __attribute__((ext_vector_type(8)));
typedef int s32x2 __attribute__((ext_vector_type(2)));
typedef u32 u32x4 __attribute__((ext_vector_type(4)));

__device__ __forceinline__ u16 f2b(float f){
  uint32_t u = __builtin_bit_cast(uint32_t, f);
  return (u16)((u + 0x7fffu + ((u >> 16) & 1u)) >> 16);  // RNE
}

__device__ __forceinline__ u32 pkbf(float lo, float hi){
  u32 r;
  asm("v_cvt_pk_bf16_f32 %0, %1, %2" : "=v"(r) : "v"(lo), "v"(hi));
  return r;
}

// ---------------- workspace layout (bytes) ----------------
constexpr size_t OFF_CW1   = 0;                                     // 3x1024x1024 bf16
constexpr size_t OFF_CW2   = OFF_CW1 + 3ull*1024*1024*2;
constexpr size_t OFF_WQKV  = OFF_CW2 + 3ull*1024*1024*2;            // 3072x1024 bf16 (q scaled 1/8)
constexpr size_t OFF_WO    = OFF_WQKV + 3072ull*1024*2;
constexpr size_t OFF_W1    = OFF_WO + 1024ull*1024*2;
constexpr size_t OFF_W2    = OFF_W1 + 4096ull*1024*2;
constexpr size_t OFF_PRE   = OFF_W2 + 4096ull*1024*2;               // f32 4096x1024
constexpr size_t OFF_QKVB  = OFF_PRE + (size_t)NTOK*1024*4;         // bf16 4096x3072
constexpr size_t OFF_INTER = OFF_PRE;                               // alias: bf16 4096x4096
constexpr size_t OFF_XPAD  = OFF_QKVB + (size_t)NTOK*3072*2;        // bf16 2x2050x1024
constexpr size_t OFF_LNF   = OFF_XPAD;                              // alias
constexpr size_t OFF_HPAD  = OFF_XPAD + (size_t)NB*SP*1024*2;       // bf16 2x2050x1024
constexpr size_t OFF_CTX   = OFF_HPAD;                              // alias
constexpr size_t OFF_INPUTS= OFF_HPAD + (size_t)NB*SP*1024*2;       // f32 4096x1024
constexpr size_t OFF_XN    = OFF_INPUTS + (size_t)NTOK*1024*4;      // bf16 4096x1024

// ---------------- pack kernels ----------------
__global__ void pack_scale_k(const float* __restrict__ in, u16* __restrict__ out, int n, float scale){
  int i = blockIdx.x*256 + threadIdx.x;
  if (i < n) out[i] = f2b(in[i]*scale);
}

// w[o][i][t] (D,D,3) -> out[t][o][i] bf16
__global__ void pack_convw_k(const float* __restrict__ w, u16* __restrict__ out){
  int i = blockIdx.x*256 + threadIdx.x;   // over 3*1024*1024
  int t = i >> 20;
  int rem = i & 1048575;
  int o = rem >> 10;
  int c = rem & 1023;
  out[i] = f2b(w[o*3072 + c*3 + t]);
}

// x f32 (B,S,D) -> xpad bf16 (B,S+2,D), zero halo rows
__global__ void pad_x_k(const float* __restrict__ x, u16* __restrict__ xp){
  int row = blockIdx.x;  // 0..NB*SP-1
  int tid = threadIdx.x;
  int b = row / SP, s = row - b*SP;
  ushort4 st;
  if (s == 0 || s == SP-1){ st.x=0; st.y=0; st.z=0; st.w=0; }
  else {
    float4 v = ((const float4*)(x + ((size_t)b*SB + s-1)*DD))[tid];
    st.x=f2b(v.x); st.y=f2b(v.y); st.z=f2b(v.z); st.w=f2b(v.w);
  }
  ((ushort4*)(xp + (size_t)row*DD))[tid] = st;
}

// out += b2[col]*mask[row]  (FFN2 bias/mask pre-pass; runs after lnF consumed out)
__global__ void bias_mask_k(float* __restrict__ out, const float* __restrict__ b2,
                            const float* __restrict__ mask){
  int i = blockIdx.x*256 + threadIdx.x;   // float4 index over 4096x1024
  int row = i >> 8, c4 = i & 255;
  float4 o = ((float4*)out)[i];
  float4 b = ((const float4*)b2)[c4];
  float m = mask[row];
  o.x += b.x*m; o.y += b.y*m; o.z += b.z*m; o.w += b.w*m;
  ((float4*)out)[i] = o;
}

// ---------------- LayerNorm ----------------
template<int MODE>
__global__ __launch_bounds__(256) void ln_k(const float* __restrict__ in, const float* __restrict__ cb,
    const float* __restrict__ g, const float* __restrict__ be, const float* __restrict__ resid,
    float* __restrict__ outf, u16* __restrict__ outb)
{
  int row = blockIdx.x, tid = threadIdx.x;
  int inrow = row;
  if (MODE == 0){
    int b = row / SP, s = row - b*SP;
    if (s == 0 || s == SP-1){
      ushort4 z; z.x=0; z.y=0; z.z=0; z.w=0;
      ((ushort4*)(outb + (size_t)row*DD))[tid] = z;
      return;
    }
    inrow = b*SB + s - 1;
  }
  float4 v = ((const float4*)(in + (size_t)inrow*DD))[tid];
  if (MODE <= 1){
    float4 c = ((const float4*)cb)[tid];
    v.x = fmaxf(v.x + c.x, 0.f);
    v.y = fmaxf(v.y + c.y, 0.f);
    v.z = fmaxf(v.z + c.z, 0.f);
    v.w = fmaxf(v.w + c.w, 0.f);
  }
  float s1 = v.x+v.y+v.z+v.w;
  float s2 = v.x*v.x + v.y*v.y + v.z*v.z + v.w*v.w;
  #pragma unroll
  for (int d=32; d>=1; d>>=1){ s1 += __shfl_down(s1, d); s2 += __shfl_down(s2, d); }
  __shared__ float red[8];
  int wid = tid >> 6, lane = tid & 63;
  if (lane==0){ red[wid] = s1; red[4+wid] = s2; }
  __syncthreads();
  s1 = red[0]+red[1]+red[2]+red[3];
  s2 = red[4]+red[5]+red[6]+red[7];
  float mu = s1 * (1.f/DD);
  float var = s2 * (1.f/DD) - mu*mu;
  float rs = rsqrtf(var + 1e-6f);
  float4 gg = ((const float4*)g)[tid];
  float4 bb = ((const float4*)be)[tid];
  float o0 = (v.x-mu)*rs*gg.x + bb.x;
  float o1 = (v.y-mu)*rs*gg.y + bb.y;
  float o2 = (v.z-mu)*rs*gg.z + bb.z;
  float o3 = (v.w-mu)*rs*gg.w + bb.w;
  if (MODE == 1){
    float4 rr = ((const float4*)(resid + (size_t)inrow*DD))[tid];
    float4 o; o.x=o0+rr.x; o.y=o1+rr.y; o.z=o2+rr.z; o.w=o3+rr.w;
    ((float4*)(outf + (size_t)inrow*DD))[tid] = o;
  } else {
    ushort4 st; st.x=f2b(o0); st.y=f2b(o1); st.z=f2b(o2); st.w=f2b(o3);
    ((ushort4*)(outb + (size_t)row*DD))[tid] = st;
  }
}

// ---------------- shared GEMM helpers ----------------
__device__ __forceinline__ void glds16(const u16* g, u16* l){
  __builtin_amdgcn_global_load_lds((const __attribute__((address_space(1))) void*)g,
                                   (__attribute__((address_space(3))) void*)l, 16, 0, 0);
}

// stage a [128 rows][64 cols] bf16 tile (16KB) with 512 threads, XOR-swizzled
// via pre-swizzled GLOBAL source (global_load_lds writes linearly).
__device__ __forceinline__ void stage_tile8(const u16* __restrict__ src, int strideK, u16* lds, int wid, int lane){
  #pragma unroll
  for (int i=0;i<2;i++){
    int chunk = (wid<<1) + i;            // 16 chunks x 1KB
    int p = (chunk<<10) + (lane<<4);     // linear LDS byte this lane fills
    int row = p >> 7;
    int clg = (p & 127) ^ ((row & 7) << 4);
    glds16(src + (size_t)row*strideK + (clg>>1), lds + (chunk<<9));
  }
}

__device__ __forceinline__ s16x8 ldsrd(const u16* slot, int r, int ks, int hi){
  int off = (r<<7) + (((ks<<6)+(hi<<4)) ^ ((r&7)<<4));
  return *(const s16x8*)((const char*)slot + off);
}

// ---------------- 8-phase 256x256 GEMM (C = A @ B^T) ----------------
// 512 thr = 8 waves (2M x 4N); per-wave C 128x64 (rows h*128+wr*64, cols
// g*128+wc*32); phase (h,g) does 16 MFMA. MODE: 0 plain, 1 conv-tap(z), 2 K-colsplit(z).
// EPI: 1 bias, 2 relu, 8 *rowmask, 16 bf16-out, 32 atomicAdd-f32.
__device__ __forceinline__ void rdA8(const u16* sA, int wr, int lr, int hi, s16x8 af[2][4]){
  #pragma unroll
  for (int ks=0;ks<2;ks++)
    #pragma unroll
    for (int m=0;m<4;m++)
      af[ks][m] = ldsrd(sA, (wr<<6)+(m<<4)+lr, ks, hi);
}
__device__ __forceinline__ void rdB8(const u16* sB, int wc, int lr, int hi, s16x8 bf[2][2]){
  #pragma unroll
  for (int ks=0;ks<2;ks++)
    #pragma unroll
    for (int n=0;n<2;n++)
      bf[ks][n] = ldsrd(sB, (wc<<5)+(n<<4)+lr, ks, hi);
}
__device__ __forceinline__ void mm16(const s16x8 af[2][4], const s16x8 bf[2][2], f32x4 a[4][2]){
  #pragma unroll
  for (int ks=0;ks<2;ks++)
    #pragma unroll
    for (int m=0;m<4;m++)
      #pragma unroll
      for (int n=0;n<2;n++)
        a[m][n] = __builtin_amdgcn_mfma_f32_16x16x32_bf16(af[ks][m], bf[ks][n], a[m][n], 0,0,0);
}

template<int EPI, int MODE>
__global__ __launch_bounds__(512,2) void gemm8(const u16* __restrict__ A, const u16* __restrict__ Bm,
    int N, int K, int lda, int ldb,
    const float* __restrict__ bias, const float* __restrict__ rowmask,
    float* __restrict__ Cf, u16* __restrict__ Cb)
{
  __shared__ __attribute__((aligned(16))) u16 Lsh[8*8192];   // 8 x 16KB half-slots
  int tid=threadIdx.x, wid=tid>>6, lane=tid&63, lr=lane&15, hi=lane>>4;
  int wr=wid>>2, wc=wid&3;
  int m0=blockIdx.x<<8, n0=blockIdx.y<<8;
  int z = blockIdx.z;
  const u16* Abase; const u16* Bbase;
  if (MODE == 1){
    Abase = A + (size_t)(m0 + 2*(m0>>11) + z)*lda;           // padded-row shift + tap
    Bbase = Bm + ((size_t)z<<20) + (size_t)n0*ldb;
  } else if (MODE == 2){
    Abase = A + (size_t)m0*lda + ((size_t)z<<10);            // K-column split
    Bbase = Bm + (size_t)n0*ldb + ((size_t)z<<10);
  } else {
    Abase = A + (size_t)m0*lda;
    Bbase = Bm + (size_t)n0*ldb;
  }
  int NT = K >> 6;
  f32x4 acc[2][2][4][2] = {};
  s16x8 af[2][4], bf[2][2];

#define LB(isB,half,par) (Lsh + ((((isB)<<2)|((half)<<1)|(par))<<13))

  // prologue: stage Aa0,Ba0,Ab0,Bb0,Aa1,Ba1
  stage_tile8(Abase,                        lda, LB(0,0,0), wid, lane);
  stage_tile8(Bbase,                        ldb, LB(1,0,0), wid, lane);
  stage_tile8(Abase + (size_t)128*lda,      lda, LB(0,1,0), wid, lane);
  stage_tile8(Bbase + (size_t)128*ldb,      ldb, LB(1,1,0), wid, lane);
  stage_tile8(Abase + 64,                   lda, LB(0,0,1), wid, lane);
  stage_tile8(Bbase + 64,                   ldb, LB(1,0,1), wid, lane);
  asm volatile("s_waitcnt vmcnt(8)" ::: "memory");
  __builtin_amdgcn_s_barrier();

#define PH(h_, g_, p_, doA, sIsB, sHalf, sTile) do{ \
    if (doA) rdA8(LB(0,h_,p_), wr, lr, hi, af); \
    rdB8(LB(1,g_,p_), wc, lr, hi, bf); \
    { int tt=(sTile); int tc = (tt<NT)? tt : (NT-2+(tt&1)); \
      const u16* ss = ((sIsB)? Bbase : Abase) + (size_t)((sHalf)*128)*((sIsB)? ldb : lda) + ((size_t)tc<<6); \
      stage_tile8(ss, (sIsB)? ldb : lda, LB(sIsB,sHalf,tc&1), wid, lane); } \
    asm volatile("s_waitcnt vmcnt(6)" ::: "memory"); \
    __builtin_amdgcn_s_barrier(); \
    asm volatile("s_waitcnt lgkmcnt(0)" ::: "memory"); \
    __builtin_amdgcn_sched_barrier(0); \
    __builtin_amdgcn_s_setprio(1); \
    mm16(af, bf, acc[h_][g_]); \
    __builtin_amdgcn_s_setprio(0); \
    __builtin_amdgcn_sched_barrier(0); \
    __builtin_amdgcn_s_barrier(); \
  }while(0)

  int half = NT>>1;
  for (int i=0; i<half; ++i){
    int t1 = 2*i+1, t2 = 2*i+2, t3 = 2*i+3;
    PH(0,0, 0, true,  0,1, t1);   // compute tile 2i q(0,0); stage Ab(2i+1)
    PH(0,1, 0, false, 1,1, t1);   // q(0,1); stage Bb(2i+1)
    PH(1,0, 0, true,  0,0, t2);   // q(1,0); stage Aa(2i+2)
    PH(1,1, 0, false, 1,0, t2);   // q(1,1); stage Ba(2i+2)
    PH(0,0, 1, true,  0,1, t2);   // tile 2i+1; stage Ab(2i+2)
    PH(0,1, 1, false, 1,1, t2);   // stage Bb(2i+2)
    PH(1,0, 1, true,  0,0, t3);   // stage Aa(2i+3)
    PH(1,1, 1, false, 1,0, t3);   // stage Ba(2i+3)
  }
#undef PH
#undef LB

  // epilogue
  #pragma unroll
  for (int h=0;h<2;h++)
    #pragma unroll
    for (int m=0;m<4;m++)
      #pragma unroll
      for (int r=0;r<4;r++){
        int row = m0 + (h<<7) + (wr<<6) + (m<<4) + (hi<<2) + r;
        float rm = (EPI&8) ? rowmask[row] : 1.f;
        #pragma unroll
        for (int g=0;g<2;g++)
          #pragma unroll
          for (int n=0;n<2;n++){
            int col = n0 + (g<<7) + (wc<<5) + (n<<4) + lr;
            float v = acc[h][g][m][n][r];
            if (EPI&1) v += bias[col];
            if (EPI&2) v = fmaxf(v, 0.f);
            if (EPI&8) v *= rm;
            if (EPI&32) atomicAdd(&Cf[(size_t)row*N + col], v);
            else if (EPI&16) Cb[(size_t)row*N + col] = f2b(v);
            else Cf[(size_t)row*N + col] = v;
          }
      }
}

// ---------------- 2-phase 128x128 GEMM (kept for Wo) ----------------
__device__ __forceinline__ void kstep_mfma8(const u16* As, const u16* Bs, int wr, int wc, int lr, int hi, f32x4 acc[4][2]){
  s16x8 af[2][4], bf[2][2];
  #pragma unroll
  for (int ks=0; ks<2; ++ks){
    #pragma unroll
    for (int m=0;m<4;m++){
      int r = (wr<<6)+(m<<4)+lr;
      int off = (r<<7) + ((((ks<<6)+(hi<<4))) ^ ((r&7)<<4));
      af[ks][m] = *(const s16x8*)((const char*)As + off);
    }
    #pragma unroll
    for (int n=0;n<2;n++){
      int r = (wc<<5)+(n<<4)+lr;
      int off = (r<<7) + ((((ks<<6)+(hi<<4))) ^ ((r&7)<<4));
      bf[ks][n] = *(const s16x8*)((const char*)Bs + off);
    }
  }
  #pragma unroll
  for (int ks=0;ks<2;++ks)
    #pragma unroll
    for (int m=0;m<4;m++)
      #pragma unroll
      for (int n=0;n<2;n++)
        acc[m][n] = __builtin_amdgcn_mfma_f32_16x16x32_bf16(af[ks][m], bf[ks][n], acc[m][n], 0,0,0);
}

__device__ __forceinline__ void stage_tile128(const u16* __restrict__ src, int strideK, u16* lds, int wid, int lane){
  #pragma unroll
  for (int i=0;i<2;i++){
    int chunk = (wid<<1) + i;
    int p = (chunk<<10) + (lane<<4);
    int row = p >> 7;
    int clg = (p & 127) ^ ((row & 7) << 4);
    glds16(src + (size_t)row*strideK + (clg>>1), lds + (chunk<<9));
  }
}

// EPI 4 = +resid f32 out (Wo)
__global__ __launch_bounds__(512,4) void gemm_wo(const u16* __restrict__ A, const u16* __restrict__ Bm,
    const float* __restrict__ resid, float* __restrict__ Cf)
{
  __shared__ __attribute__((aligned(16))) u16 As[2][128*64];
  __shared__ __attribute__((aligned(16))) u16 Bs[2][128*64];
  const int N = 1024, K = 1024;
  int tid=threadIdx.x, wid=tid>>6, lane=tid&63, lr=lane&15, hi=lane>>4;
  int wr=wid>>2, wc=wid&3;
  int m0=blockIdx.x<<7, n0=blockIdx.y<<7;
  f32x4 acc[4][2] = {};
  const u16* Ab = A + (size_t)m0*K;
  const u16* Bb = Bm + (size_t)n0*K;
  int nk = K >> 6;
  stage_tile128(Ab, K, As[0], wid, lane);
  stage_tile128(Bb, K, Bs[0], wid, lane);
  __syncthreads();
  int cur = 0;
  for (int kt=0; kt<nk; ++kt){
    if (kt+1 < nk){
      stage_tile128(Ab + ((kt+1)<<6), K, As[cur^1], wid, lane);
      stage_tile128(Bb + ((kt+1)<<6), K, Bs[cur^1], wid, lane);
    }
    kstep_mfma8(As[cur], Bs[cur], wr, wc, lr, hi, acc);
    __syncthreads();
    cur ^= 1;
  }
  #pragma unroll
  for (int m=0;m<4;m++)
    #pragma unroll
    for (int r=0;r<4;r++){
      int row = m0 + (wr<<6) + (m<<4) + (hi<<2) + r;
      #pragma unroll
      for (int n=0;n<2;n++){
        int col = n0 + (wc<<5) + (n<<4) + lr;
        float v = acc[m][n][r] + resid[(size_t)row*N + col];
        Cf[(size_t)row*N + col] = v;
      }
    }
}

// ---------------- flash attention (round 3: 32x32 MFMA, in-reg softmax) ----
__global__ __launch_bounds__(256,2) void attn_k(const u16* __restrict__ qkv, u16* __restrict__ ctx)
{
  __shared__ __attribute__((aligned(16))) u16 Ks[2][64*64];  // [key][d], 128B rows, swz
  __shared__ __attribute__((aligned(16))) u16 Vt[64*64];     // [d][key], 128B rows, swz
  int tid=threadIdx.x, wid=tid>>6, lane=tid&63, ql=lane&31, hl=lane>>5;
  int bid = blockIdx.x;
  int hb = bid & 31, qt = bid >> 5;
  int h = hb & 15, b = hb >> 4;
  int q0 = (qt<<7) + (wid<<5);
  size_t kbase = ((size_t)b*SB)*3072 + 1024 + (h<<6);
  size_t vbase = kbase + 1024;

  s16x8 bq[4];
  {
    size_t qrow = ((size_t)b*SB + q0 + ql)*3072 + (h<<6);
    #pragma unroll
    for (int dc=0; dc<4; ++dc) bq[dc] = *(const s16x8*)(qkv + qrow + (dc<<4) + (hl<<3));
  }

  int kp = tid & 31, dgrp = tid >> 5;

  #pragma unroll
  for (int i=0;i<2;i++){
    int chunk = (wid<<1)+i;
    int p = (chunk<<10) + (lane<<4);
    int row = p>>7;
    int colb = (p&127) ^ ((row&7)<<4);
    glds16(qkv + kbase + (size_t)row*3072 + (colb>>1), Ks[0] + (chunk<<9));
  }
  s16x8 v0 = *(const s16x8*)(qkv + vbase + (size_t)(2*kp)*3072 + (dgrp<<3));
  s16x8 v1 = *(const s16x8*)(qkv + vbase + (size_t)(2*kp+1)*3072 + (dgrp<<3));

  float m_r = -1e30f, l_r = 0.f;
  f32x16 acc[2] = {};
  int cur = 0;
  for (int kt=0; kt<32; ++kt){
    __syncthreads();
    #pragma unroll
    for (int i=0;i<8;i++){
      int d = (dgrp<<3)+i;
      u32 val = ((u32)(u16)v0[i]) | (((u32)(u16)v1[i])<<16);
      *(u32*)((char*)Vt + (d<<7) + ((kp<<2) ^ ((d&7)<<4))) = val;
    }
    __syncthreads();
    if (kt+1 < 32){
      int k0n = (kt+1)<<6;
      #pragma unroll
      for (int i=0;i<2;i++){
        int chunk = (wid<<1)+i;
        int p = (chunk<<10) + (lane<<4);
        int row = p>>7;
        int colb = (p&127) ^ ((row&7)<<4);
        glds16(qkv + kbase + (size_t)(k0n+row)*3072 + (colb>>1), Ks[cur^1] + (chunk<<9));
      }
      v0 = *(const s16x8*)(qkv + vbase + (size_t)(k0n + 2*kp)*3072 + (dgrp<<3));
      v1 = *(const s16x8*)(qkv + vbase + (size_t)(k0n + 2*kp+1)*3072 + (dgrp<<3));
    }
    const char* Kb = (const char*)Ks[cur];
    f32x16 s0 = {}, s1 = {};
    #pragma unroll
    for (int dc=0; dc<4; ++dc){
      int cb = ((dc<<4) + (hl<<3)) << 1;
      {
        int row = ql;
        s16x8 ka = *(const s16x8*)(Kb + (row<<7) + (cb ^ ((row&7)<<4)));
        s0 = __builtin_amdgcn_mfma_f32_32x32x16_bf16(ka, bq[dc], s0, 0,0,0);
      }
      {
        int row = 32+ql;
        s16x8 ka = *(const s16x8*)(Kb + (row<<7) + (cb ^ ((row&7)<<4)));
        s1 = __builtin_amdgcn_mfma_f32_32x32x16_bf16(ka, bq[dc], s1, 0,0,0);
      }
    }
    float mt = s0[0];
    #pragma unroll
    for (int r=1;r<16;r++) mt = fmaxf(mt, s0[r]);
    #pragma unroll
    for (int r=0;r<16;r++) mt = fmaxf(mt, s1[r]);
    mt = fmaxf(mt, __shfl_xor(mt, 32));
    float mn = fmaxf(m_r, mt);
    float al = __expf(m_r - mn);
    m_r = mn;
    float sm = 0.f;
    #pragma unroll
    for (int r=0;r<16;r++){ s0[r] = __expf(s0[r]-mn); sm += s0[r]; }
    #pragma unroll
    for (int r=0;r<16;r++){ s1[r] = __expf(s1[r]-mn); sm += s1[r]; }
    sm += __shfl_xor(sm, 32);
    l_r = l_r*al + sm;
    acc[0] = acc[0]*al;
    acc[1] = acc[1]*al;
    s16x8 pb[4];
    #pragma unroll
    for (int c=0;c<4;c++){
      u32x4 fr;
      #pragma unroll
      for (int bp=0; bp<2; ++bp){
        int ba = 8*(c&1);
        float alo, ahi, blo, bhi;
        if (c>>1){ alo=s1[ba+2*bp]; ahi=s1[ba+2*bp+1]; blo=s1[ba+4+2*bp]; bhi=s1[ba+4+2*bp+1]; }
        else     { alo=s0[ba+2*bp]; ahi=s0[ba+2*bp+1]; blo=s0[ba+4+2*bp]; bhi=s0[ba+4+2*bp+1]; }
        u32 A = pkbf(alo, ahi);
        u32 B = pkbf(blo, bhi);
        s32x2 swp = __builtin_amdgcn_permlane32_swap((int)A, (int)B, false, false);
        fr[bp]   = (u32)swp[0];
        fr[bp+2] = (u32)swp[1];
      }
      pb[c] = __builtin_bit_cast(s16x8, fr);
    }
    #pragma unroll
    for (int dh=0; dh<2; ++dh){
      #pragma unroll
      for (int c=0;c<4;c++){
        int d = (dh<<5) + ql;
        s16x8 vf = *(const s16x8*)((const char*)Vt + (d<<7) + ((((c<<5)+(hl<<4))) ^ ((d&7)<<4)));
        acc[dh] = __builtin_amdgcn_mfma_f32_32x32x16_bf16(vf, pb[c], acc[dh], 0,0,0);
      }
    }
    cur ^= 1;
  }
  __syncthreads();
  float inv = 1.f / l_r;
  u16* Os = (u16*)Ks[0] + (wid<<11);
  #pragma unroll
  for (int dh=0; dh<2; ++dh)
    #pragma unroll
    for (int a=0;a<4;a++)
      #pragma unroll
      for (int bp=0;bp<2;bp++){
        u32 w = pkbf(acc[dh][4*a+2*bp]*inv, acc[dh][4*a+2*bp+1]*inv);
        int d2 = (dh<<5) + (a<<3) + (hl<<2) + (bp<<1);
        *(u32*)((char*)Os + (ql<<7) + (((d2<<1)) ^ ((ql&7)<<4))) = w;
      }
  int rw = lane>>1, half = lane&1;
  size_t gb = ((size_t)b*SB + q0 + rw)*DD + (h<<6) + (half<<5);
  #pragma unroll
  for (int j=0;j<4;j++){
    s16x8 o = *(const s16x8*)((const char*)Os + (rw<<7) + ((((half<<6)+(j<<4))) ^ ((rw&7)<<4)));
    *(s16x8*)(ctx + gb + (j<<3)) = o;
  }
}

// ---------------- launch ----------------
extern "C" void kernel_launch(void* const* d_in, const int* in_sizes, int n_in,
                              void* d_out, int out_size, void* d_ws, size_t ws_size,
                              hipStream_t stream)
{
  (void)in_sizes; (void)n_in; (void)out_size; (void)ws_size;
  const float* x       = (const float*)d_in[0];
  const float* ffnmask = (const float*)d_in[2];
  const float* conv1_w = (const float*)d_in[3];
  const float* conv1_b = (const float*)d_in[4];
  const float* ln1_g   = (const float*)d_in[5];
  const float* ln1_b   = (const float*)d_in[6];
  const float* conv2_w = (const float*)d_in[7];
  const float* conv2_b = (const float*)d_in[8];
  const float* ln2_g   = (const float*)d_in[9];
  const float* ln2_b   = (const float*)d_in[10];
  const float* lnA_g   = (const float*)d_in[11];
  const float* lnA_b   = (const float*)d_in[12];
  const float* Wq      = (const float*)d_in[13];
  const float* Wk      = (const float*)d_in[14];
  const float* Wv      = (const float*)d_in[15];
  const float* Wo      = (const float*)d_in[16];
  const float* lnF_g   = (const float*)d_in[17];
  const float* lnF_b   = (const float*)d_in[18];
  const float* W1      = (const float*)d_in[19];
  const float* b1      = (const float*)d_in[20];
  const float* W2      = (const float*)d_in[21];
  const float* b2      = (const float*)d_in[22];
  float* out = (float*)d_out;
  char* ws = (char*)d_ws;
  u16*  cw1    = (u16*)(ws + OFF_CW1);
  u16*  cw2    = (u16*)(ws + OFF_CW2);
  u16*  wqkv   = (u16*)(ws + OFF_WQKV);
  u16*  wo     = (u16*)(ws + OFF_WO);
  u16*  w1p    = (u16*)(ws + OFF_W1);
  u16*  w2p    = (u16*)(ws + OFF_W2);
  float* pre   = (float*)(ws + OFF_PRE);
  u16*  qkvb   = (u16*)(ws + OFF_QKVB);
  u16*  interb = (u16*)(ws + OFF_INTER);
  u16*  xpad   = (u16*)(ws + OFF_XPAD);
  u16*  lnfb   = (u16*)(ws + OFF_LNF);
  u16*  hpad   = (u16*)(ws + OFF_HPAD);
  u16*  ctxb   = (u16*)(ws + OFF_CTX);
  float* inputs= (float*)(ws + OFF_INPUTS);
  u16*  xnb    = (u16*)(ws + OFF_XN);

  // weight packs (bf16); q-scale 1/sqrt(64) folded into Wq
  pack_convw_k<<<12288, 256, 0, stream>>>(conv1_w, cw1);
  pack_convw_k<<<12288, 256, 0, stream>>>(conv2_w, cw2);
  pack_scale_k<<<4096, 256, 0, stream>>>(Wq, wqkv,             1024*1024, 0.125f);
  pack_scale_k<<<4096, 256, 0, stream>>>(Wk, wqkv + (1u<<20),  1024*1024, 1.f);
  pack_scale_k<<<4096, 256, 0, stream>>>(Wv, wqkv + (2u<<20),  1024*1024, 1.f);
  pack_scale_k<<<4096, 256, 0, stream>>>(Wo, wo,               1024*1024, 1.f);
  pack_scale_k<<<16384, 256, 0, stream>>>(W1, w1p, 4096*1024, 1.f);
  pack_scale_k<<<16384, 256, 0, stream>>>(W2, w2p, 4096*1024, 1.f);
  pad_x_k<<<NB*SP, 256, 0, stream>>>(x, xpad);

  // conv1 (8-phase, tap-split z=3, atomic into zeroed pre) -> relu -> LN1
  hipMemsetAsync(pre, 0, (size_t)NTOK*DD*4, stream);
  gemm8<32,1><<<dim3(16,4,3), 512, 0, stream>>>(xpad, cw1, 1024, 1024, 1024, 1024, nullptr, nullptr, pre, nullptr);
  ln_k<0><<<NB*SP, 256, 0, stream>>>(pre, conv1_b, ln1_g, ln1_b, nullptr, nullptr, hpad);
  // conv2 -> relu -> LN2 -> +x => inputs (f32)
  hipMemsetAsync(pre, 0, (size_t)NTOK*DD*4, stream);
  gemm8<32,1><<<dim3(16,4,3), 512, 0, stream>>>(hpad, cw2, 1024, 1024, 1024, 1024, nullptr, nullptr, pre, nullptr);
  ln_k<1><<<NTOK, 256, 0, stream>>>(pre, conv2_b, ln2_g, ln2_b, x, inputs, nullptr);
  // lnA -> xn (bf16)
  ln_k<2><<<NTOK, 256, 0, stream>>>(inputs, nullptr, lnA_g, lnA_b, nullptr, nullptr, xnb);
  // fused QKV projection (8-phase)
  gemm8<16,0><<<dim3(16,12), 512, 0, stream>>>(xnb, wqkv, 3072, 1024, 1024, 1024, nullptr, nullptr, nullptr, qkvb);
  // flash attention
  attn_k<<<512, 256, 0, stream>>>(qkvb, ctxb);
  // out = ctx @ Wo^T + inputs (2-phase 128^2, 256 blocks)
  gemm_wo<<<dim3(32,8), 512, 0, stream>>>(ctxb, wo, inputs, out);
  // lnF -> bf16
  ln_k<2><<<NTOK, 256, 0, stream>>>(out, nullptr, lnF_g, lnF_b, nullptr, nullptr, lnfb);
  // inter = relu(lnF @ W1^T + b1) (8-phase)
  gemm8<19,0><<<dim3(16,16), 512, 0, stream>>>(lnfb, w1p, 4096, 1024, 1024, 1024, b1, nullptr, nullptr, interb);
  // out += b2*mask, then FFN2 (8-phase, K-split z=4, atomic, *mask)
  bias_mask_k<<<4096, 256, 0, stream>>>(out, b2, ffnmask);
  gemm8<40,2><<<dim3(16,4,4), 512, 0, stream>>>(interb, w2p, 1024, 1024, 4096, 4096, nullptr, ffnmask, out, nullptr);
}

// Round 6
// 411.668 us; speedup vs baseline: 1.0880x; 1.0880x over previous
//
#include <hip/hip_runtime.h>
#include <hip/hip_bf16.h>
#include <cstdint>
#include <cstddef>

// TransformerEncoderLayer: B=2 S=2048 D=1024 H=16 DH=64 DFF=4096, fp32 in/out.
// Round 5: (a) drop all atomic split-K (r4 regression): convs+FFN2 back to
// 2-phase 128^2 512-thr GEMM with fused epilogues. (b) attention KV-split z=2
// (grid 1024, 50% occupancy cap) with bf16 partial accumulators + LSE-merge
// combine pass; softmax in exp2 domain (log2e folded into Wq pack).

#define SB 2048
#define DD 1024
#define NB 2
#define NH 16
#define DFF_ 4096
#define NTOK (NB*SB)   // 4096
#define SP (SB+2)      // 2050 (padded rows for conv halo)

typedef unsigned short u16;
typedef unsigned int u32;
typedef float f32x4 __attribute__((ext_vector_type(4)));
typedef float f32x16 __attribute__((ext_vector_type(16)));
typedef short s16x8 __attribute__((ext_vector_type(8)));
typedef int s32x2 __attribute__((ext_vector_type(2)));
typedef u32 u32x4 __attribute__((ext_vector_type(4)));

__device__ __forceinline__ u16 f2b(float f){
  uint32_t u = __builtin_bit_cast(uint32_t, f);
  return (u16)((u + 0x7fffu + ((u >> 16) & 1u)) >> 16);  // RNE
}
__device__ __forceinline__ float b2f(u16 u){
  return __builtin_bit_cast(float, ((u32)u)<<16);
}
__device__ __forceinline__ u32 pkbf(float lo, float hi){
  u32 r;
  asm("v_cvt_pk_bf16_f32 %0, %1, %2" : "=v"(r) : "v"(lo), "v"(hi));
  return r;
}

// ---------------- workspace layout (bytes) ----------------
constexpr size_t OFF_CW1   = 0;                                     // 3x1024x1024 bf16
constexpr size_t OFF_CW2   = OFF_CW1 + 3ull*1024*1024*2;
constexpr size_t OFF_WQKV  = OFF_CW2 + 3ull*1024*1024*2;            // 3072x1024 bf16 (q scaled log2e/8)
constexpr size_t OFF_WO    = OFF_WQKV + 3072ull*1024*2;
constexpr size_t OFF_W1    = OFF_WO + 1024ull*1024*2;
constexpr size_t OFF_W2    = OFF_W1 + 4096ull*1024*2;
constexpr size_t OFF_PRE   = OFF_W2 + 4096ull*1024*2;               // f32 4096x1024
constexpr size_t OFF_APART = OFF_PRE;                               // alias: bf16 2 x 4096x1024 (attn partials)
constexpr size_t OFF_QKVB  = OFF_PRE + (size_t)NTOK*1024*4;         // bf16 4096x3072
constexpr size_t OFF_INTER = OFF_PRE;                               // alias: bf16 4096x4096
constexpr size_t OFF_XPAD  = OFF_QKVB + (size_t)NTOK*3072*2;        // bf16 2x2050x1024
constexpr size_t OFF_LNF   = OFF_XPAD;                              // alias
constexpr size_t OFF_HPAD  = OFF_XPAD + (size_t)NB*SP*1024*2;       // bf16 2x2050x1024
constexpr size_t OFF_CTX   = OFF_HPAD;                              // alias
constexpr size_t OFF_INPUTS= OFF_HPAD + (size_t)NB*SP*1024*2;       // f32 4096x1024
constexpr size_t OFF_XN    = OFF_INPUTS + (size_t)NTOK*1024*4;      // bf16 4096x1024
constexpr size_t OFF_ML    = OFF_XN;                                // alias: f32 2 x 4096 x 16 x 2 (attn m,l)

// ---------------- pack kernels ----------------
__global__ void pack_scale_k(const float* __restrict__ in, u16* __restrict__ out, int n, float scale){
  int i = blockIdx.x*256 + threadIdx.x;
  if (i < n) out[i] = f2b(in[i]*scale);
}

// w[o][i][t] (D,D,3) -> out[t][o][i] bf16
__global__ void pack_convw_k(const float* __restrict__ w, u16* __restrict__ out){
  int i = blockIdx.x*256 + threadIdx.x;   // over 3*1024*1024
  int t = i >> 20;
  int rem = i & 1048575;
  int o = rem >> 10;
  int c = rem & 1023;
  out[i] = f2b(w[o*3072 + c*3 + t]);
}

// x f32 (B,S,D) -> xpad bf16 (B,S+2,D), zero halo rows
__global__ void pad_x_k(const float* __restrict__ x, u16* __restrict__ xp){
  int row = blockIdx.x;  // 0..NB*SP-1
  int tid = threadIdx.x;
  int b = row / SP, s = row - b*SP;
  ushort4 st;
  if (s == 0 || s == SP-1){ st.x=0; st.y=0; st.z=0; st.w=0; }
  else {
    float4 v = ((const float4*)(x + ((size_t)b*SB + s-1)*DD))[tid];
    st.x=f2b(v.x); st.y=f2b(v.y); st.z=f2b(v.z); st.w=f2b(v.w);
  }
  ((ushort4*)(xp + (size_t)row*DD))[tid] = st;
}

// ---------------- LayerNorm ----------------
template<int MODE>
__global__ __launch_bounds__(256) void ln_k(const float* __restrict__ in, const float* __restrict__ cb,
    const float* __restrict__ g, const float* __restrict__ be, const float* __restrict__ resid,
    float* __restrict__ outf, u16* __restrict__ outb)
{
  int row = blockIdx.x, tid = threadIdx.x;
  int inrow = row;
  if (MODE == 0){
    int b = row / SP, s = row - b*SP;
    if (s == 0 || s == SP-1){
      ushort4 z; z.x=0; z.y=0; z.z=0; z.w=0;
      ((ushort4*)(outb + (size_t)row*DD))[tid] = z;
      return;
    }
    inrow = b*SB + s - 1;
  }
  float4 v = ((const float4*)(in + (size_t)inrow*DD))[tid];
  if (MODE <= 1){
    float4 c = ((const float4*)cb)[tid];
    v.x = fmaxf(v.x + c.x, 0.f);
    v.y = fmaxf(v.y + c.y, 0.f);
    v.z = fmaxf(v.z + c.z, 0.f);
    v.w = fmaxf(v.w + c.w, 0.f);
  }
  float s1 = v.x+v.y+v.z+v.w;
  float s2 = v.x*v.x + v.y*v.y + v.z*v.z + v.w*v.w;
  #pragma unroll
  for (int d=32; d>=1; d>>=1){ s1 += __shfl_down(s1, d); s2 += __shfl_down(s2, d); }
  __shared__ float red[8];
  int wid = tid >> 6, lane = tid & 63;
  if (lane==0){ red[wid] = s1; red[4+wid] = s2; }
  __syncthreads();
  s1 = red[0]+red[1]+red[2]+red[3];
  s2 = red[4]+red[5]+red[6]+red[7];
  float mu = s1 * (1.f/DD);
  float var = s2 * (1.f/DD) - mu*mu;
  float rs = rsqrtf(var + 1e-6f);
  float4 gg = ((const float4*)g)[tid];
  float4 bb = ((const float4*)be)[tid];
  float o0 = (v.x-mu)*rs*gg.x + bb.x;
  float o1 = (v.y-mu)*rs*gg.y + bb.y;
  float o2 = (v.z-mu)*rs*gg.z + bb.z;
  float o3 = (v.w-mu)*rs*gg.w + bb.w;
  if (MODE == 1){
    float4 rr = ((const float4*)(resid + (size_t)inrow*DD))[tid];
    float4 o; o.x=o0+rr.x; o.y=o1+rr.y; o.z=o2+rr.z; o.w=o3+rr.w;
    ((float4*)(outf + (size_t)inrow*DD))[tid] = o;
  } else {
    ushort4 st; st.x=f2b(o0); st.y=f2b(o1); st.z=f2b(o2); st.w=f2b(o3);
    ((ushort4*)(outb + (size_t)row*DD))[tid] = st;
  }
}

// ---------------- shared GEMM helpers ----------------
__device__ __forceinline__ void glds16(const u16* g, u16* l){
  __builtin_amdgcn_global_load_lds((const __attribute__((address_space(1))) void*)g,
                                   (__attribute__((address_space(3))) void*)l, 16, 0, 0);
}

// stage a [128 rows][64 cols] bf16 tile (16KB) with 512 threads, XOR-swizzled
// via pre-swizzled GLOBAL source (global_load_lds writes linearly).
__device__ __forceinline__ void stage_tile8(const u16* __restrict__ src, int strideK, u16* lds, int wid, int lane){
  #pragma unroll
  for (int i=0;i<2;i++){
    int chunk = (wid<<1) + i;            // 16 chunks x 1KB
    int p = (chunk<<10) + (lane<<4);     // linear LDS byte this lane fills
    int row = p >> 7;
    int clg = (p & 127) ^ ((row & 7) << 4);
    glds16(src + (size_t)row*strideK + (clg>>1), lds + (chunk<<9));
  }
}

__device__ __forceinline__ s16x8 ldsrd(const u16* slot, int r, int ks, int hi){
  int off = (r<<7) + (((ks<<6)+(hi<<4)) ^ ((r&7)<<4));
  return *(const s16x8*)((const char*)slot + off);
}

__device__ __forceinline__ void kstep_mfma8(const u16* As, const u16* Bs, int wr, int wc, int lr, int hi, f32x4 acc[4][2]){
  s16x8 af[2][4], bf[2][2];
  #pragma unroll
  for (int ks=0; ks<2; ++ks){
    #pragma unroll
    for (int m=0;m<4;m++) af[ks][m] = ldsrd(As, (wr<<6)+(m<<4)+lr, ks, hi);
    #pragma unroll
    for (int n=0;n<2;n++) bf[ks][n] = ldsrd(Bs, (wc<<5)+(n<<4)+lr, ks, hi);
  }
  #pragma unroll
  for (int ks=0;ks<2;++ks)
    #pragma unroll
    for (int m=0;m<4;m++)
      #pragma unroll
      for (int n=0;n<2;n++)
        acc[m][n] = __builtin_amdgcn_mfma_f32_16x16x32_bf16(af[ks][m], bf[ks][n], acc[m][n], 0,0,0);
}

// ---------------- 8-phase 256x256 GEMM (C = A @ B^T), plain-store ----------
// EPI: 1 bias, 2 relu, 16 bf16-out (else f32).
__device__ __forceinline__ void rdA8(const u16* sA, int wr, int lr, int hi, s16x8 af[2][4]){
  #pragma unroll
  for (int ks=0;ks<2;ks++)
    #pragma unroll
    for (int m=0;m<4;m++)
      af[ks][m] = ldsrd(sA, (wr<<6)+(m<<4)+lr, ks, hi);
}
__device__ __forceinline__ void rdB8(const u16* sB, int wc, int lr, int hi, s16x8 bf[2][2]){
  #pragma unroll
  for (int ks=0;ks<2;ks++)
    #pragma unroll
    for (int n=0;n<2;n++)
      bf[ks][n] = ldsrd(sB, (wc<<5)+(n<<4)+lr, ks, hi);
}
__device__ __forceinline__ void mm16(const s16x8 af[2][4], const s16x8 bf[2][2], f32x4 a[4][2]){
  #pragma unroll
  for (int ks=0;ks<2;ks++)
    #pragma unroll
    for (int m=0;m<4;m++)
      #pragma unroll
      for (int n=0;n<2;n++)
        a[m][n] = __builtin_amdgcn_mfma_f32_16x16x32_bf16(af[ks][m], bf[ks][n], a[m][n], 0,0,0);
}

template<int EPI>
__global__ __launch_bounds__(512,2) void gemm8(const u16* __restrict__ A, const u16* __restrict__ Bm,
    int N, int K, const float* __restrict__ bias,
    float* __restrict__ Cf, u16* __restrict__ Cb)
{
  __shared__ __attribute__((aligned(16))) u16 Lsh[8*8192];   // 8 x 16KB half-slots
  int tid=threadIdx.x, wid=tid>>6, lane=tid&63, lr=lane&15, hi=lane>>4;
  int wr=wid>>2, wc=wid&3;
  int m0=blockIdx.x<<8, n0=blockIdx.y<<8;
  const u16* Abase = A + (size_t)m0*K;
  const u16* Bbase = Bm + (size_t)n0*K;
  int NT = K >> 6;
  f32x4 acc[2][2][4][2] = {};
  s16x8 af[2][4], bf[2][2];

#define LB(isB,half,par) (Lsh + ((((isB)<<2)|((half)<<1)|(par))<<13))
  stage_tile8(Abase,                   K, LB(0,0,0), wid, lane);
  stage_tile8(Bbase,                   K, LB(1,0,0), wid, lane);
  stage_tile8(Abase + (size_t)128*K,   K, LB(0,1,0), wid, lane);
  stage_tile8(Bbase + (size_t)128*K,   K, LB(1,1,0), wid, lane);
  stage_tile8(Abase + 64,              K, LB(0,0,1), wid, lane);
  stage_tile8(Bbase + 64,              K, LB(1,0,1), wid, lane);
  asm volatile("s_waitcnt vmcnt(8)" ::: "memory");
  __builtin_amdgcn_s_barrier();

#define PH(h_, g_, p_, doA, sIsB, sHalf, sTile) do{ \
    if (doA) rdA8(LB(0,h_,p_), wr, lr, hi, af); \
    rdB8(LB(1,g_,p_), wc, lr, hi, bf); \
    { int tt=(sTile); int tc = (tt<NT)? tt : (NT-2+(tt&1)); \
      const u16* ss = ((sIsB)? Bbase : Abase) + (size_t)((sHalf)*128)*K + ((size_t)tc<<6); \
      stage_tile8(ss, K, LB(sIsB,sHalf,tc&1), wid, lane); } \
    asm volatile("s_waitcnt vmcnt(6)" ::: "memory"); \
    __builtin_amdgcn_s_barrier(); \
    asm volatile("s_waitcnt lgkmcnt(0)" ::: "memory"); \
    __builtin_amdgcn_sched_barrier(0); \
    __builtin_amdgcn_s_setprio(1); \
    mm16(af, bf, acc[h_][g_]); \
    __builtin_amdgcn_s_setprio(0); \
    __builtin_amdgcn_sched_barrier(0); \
    __builtin_amdgcn_s_barrier(); \
  }while(0)

  int half = NT>>1;
  for (int i=0; i<half; ++i){
    int t1 = 2*i+1, t2 = 2*i+2, t3 = 2*i+3;
    PH(0,0, 0, true,  0,1, t1);
    PH(0,1, 0, false, 1,1, t1);
    PH(1,0, 0, true,  0,0, t2);
    PH(1,1, 0, false, 1,0, t2);
    PH(0,0, 1, true,  0,1, t2);
    PH(0,1, 1, false, 1,1, t2);
    PH(1,0, 1, true,  0,0, t3);
    PH(1,1, 1, false, 1,0, t3);
  }
#undef PH
#undef LB

  #pragma unroll
  for (int h=0;h<2;h++)
    #pragma unroll
    for (int m=0;m<4;m++)
      #pragma unroll
      for (int r=0;r<4;r++){
        int row = m0 + (h<<7) + (wr<<6) + (m<<4) + (hi<<2) + r;
        #pragma unroll
        for (int g=0;g<2;g++)
          #pragma unroll
          for (int n=0;n<2;n++){
            int col = n0 + (g<<7) + (wc<<5) + (n<<4) + lr;
            float v = acc[h][g][m][n][r];
            if (EPI&1) v += bias[col];
            if (EPI&2) v = fmaxf(v, 0.f);
            if (EPI&16) Cb[(size_t)row*N + col] = f2b(v);
            else Cf[(size_t)row*N + col] = v;
          }
      }
}

// ---------------- 2-phase 128x128 GEMMs ----------------
// Wo: C = A@B^T + resid (f32 out)
__global__ __launch_bounds__(512,4) void gemm_wo(const u16* __restrict__ A, const u16* __restrict__ Bm,
    const float* __restrict__ resid, float* __restrict__ Cf)
{
  __shared__ __attribute__((aligned(16))) u16 As[2][128*64];
  __shared__ __attribute__((aligned(16))) u16 Bs[2][128*64];
  const int N = 1024, K = 1024;
  int tid=threadIdx.x, wid=tid>>6, lane=tid&63, lr=lane&15, hi=lane>>4;
  int wr=wid>>2, wc=wid&3;
  int m0=blockIdx.x<<7, n0=blockIdx.y<<7;
  f32x4 acc[4][2] = {};
  const u16* Ab = A + (size_t)m0*K;
  const u16* Bb = Bm + (size_t)n0*K;
  int nk = K >> 6;
  stage_tile8(Ab, K, As[0], wid, lane);
  stage_tile8(Bb, K, Bs[0], wid, lane);
  __syncthreads();
  int cur = 0;
  for (int kt=0; kt<nk; ++kt){
    if (kt+1 < nk){
      stage_tile8(Ab + ((kt+1)<<6), K, As[cur^1], wid, lane);
      stage_tile8(Bb + ((kt+1)<<6), K, Bs[cur^1], wid, lane);
    }
    kstep_mfma8(As[cur], Bs[cur], wr, wc, lr, hi, acc);
    __syncthreads();
    cur ^= 1;
  }
  #pragma unroll
  for (int m=0;m<4;m++)
    #pragma unroll
    for (int r=0;r<4;r++){
      int row = m0 + (wr<<6) + (m<<4) + (hi<<2) + r;
      #pragma unroll
      for (int n=0;n<2;n++){
        int col = n0 + (wc<<5) + (n<<4) + lr;
        Cf[(size_t)row*N + col] = acc[m][n][r] + resid[(size_t)row*N + col];
      }
    }
}

// FFN2: out = (A@B^T + b2)*mask[row] + out  (K=4096, f32 in-place)
__global__ __launch_bounds__(512,4) void gemm_f2(const u16* __restrict__ A, const u16* __restrict__ Bm,
    const float* __restrict__ bias, const float* __restrict__ mask, float* __restrict__ Cf)
{
  __shared__ __attribute__((aligned(16))) u16 As[2][128*64];
  __shared__ __attribute__((aligned(16))) u16 Bs[2][128*64];
  const int N = 1024, K = 4096;
  int tid=threadIdx.x, wid=tid>>6, lane=tid&63, lr=lane&15, hi=lane>>4;
  int wr=wid>>2, wc=wid&3;
  int m0=blockIdx.x<<7, n0=blockIdx.y<<7;
  f32x4 acc[4][2] = {};
  const u16* Ab = A + (size_t)m0*K;
  const u16* Bb = Bm + (size_t)n0*K;
  int nk = K >> 6;
  stage_tile8(Ab, K, As[0], wid, lane);
  stage_tile8(Bb, K, Bs[0], wid, lane);
  __syncthreads();
  int cur = 0;
  for (int kt=0; kt<nk; ++kt){
    if (kt+1 < nk){
      stage_tile8(Ab + ((kt+1)<<6), K, As[cur^1], wid, lane);
      stage_tile8(Bb + ((kt+1)<<6), K, Bs[cur^1], wid, lane);
    }
    kstep_mfma8(As[cur], Bs[cur], wr, wc, lr, hi, acc);
    __syncthreads();
    cur ^= 1;
  }
  #pragma unroll
  for (int m=0;m<4;m++)
    #pragma unroll
    for (int r=0;r<4;r++){
      int row = m0 + (wr<<6) + (m<<4) + (hi<<2) + r;
      float rm = mask[row];
      #pragma unroll
      for (int n=0;n<2;n++){
        int col = n0 + (wc<<5) + (n<<4) + lr;
        float v = (acc[m][n][r] + bias[col])*rm + Cf[(size_t)row*N + col];
        Cf[(size_t)row*N + col] = v;
      }
    }
}

// conv as GEMM over padded activations, taps flattened (2-phase, plain f32 out)
__global__ __launch_bounds__(512,4) void conv_gemm(const u16* __restrict__ xp, const u16* __restrict__ W3,
    float* __restrict__ Cf)
{
  __shared__ __attribute__((aligned(16))) u16 As[2][128*64];
  __shared__ __attribute__((aligned(16))) u16 Bs[2][128*64];
  int tid=threadIdx.x, wid=tid>>6, lane=tid&63, lr=lane&15, hi=lane>>4;
  int wr=wid>>2, wc=wid&3;
  int m0=blockIdx.x<<7, n0=blockIdx.y<<7;
  int bb = m0 >> 11, ss = m0 & 2047;
  f32x4 acc[4][2] = {};
  const u16* ab0 = xp + ((size_t)bb*SP + ss)*DD;
  const u16* bb0 = W3 + ((size_t)n0<<10);
  stage_tile8(ab0, DD, As[0], wid, lane);
  stage_tile8(bb0, DD, Bs[0], wid, lane);
  __syncthreads();
  int cur = 0;
  for (int idx=0; idx<48; ++idx){
    if (idx+1 < 48){
      int tap = (idx+1)>>4, kt = (idx+1)&15;
      stage_tile8(ab0 + (size_t)tap*DD + (kt<<6), DD, As[cur^1], wid, lane);
      stage_tile8(bb0 + ((size_t)tap<<20) + (kt<<6), DD, Bs[cur^1], wid, lane);
    }
    kstep_mfma8(As[cur], Bs[cur], wr, wc, lr, hi, acc);
    __syncthreads();
    cur ^= 1;
  }
  #pragma unroll
  for (int m=0;m<4;m++)
    #pragma unroll
    for (int r=0;r<4;r++){
      int row = m0 + (wr<<6) + (m<<4) + (hi<<2) + r;
      #pragma unroll
      for (int n=0;n<2;n++){
        int col = n0 + (wc<<5) + (n<<4) + lr;
        Cf[(size_t)row*DD + col] = acc[m][n][r];
      }
    }
}

// ---------------- flash attention, KV-split z=2 ----------------
// qkv: [NTOK][3072] bf16 = [q k v], q pre-scaled by log2e/8 (exp2 domain).
// Grid 1024: hb=bid&31 (h,b), z=(bid>>5)&1 (KV half), qt=bid>>6. 4 waves,
// wave owns 32 q rows; 16 KV tiles of 64 keys. Outputs UNNORMALIZED partial
// A (bf16) + per-(q,h) m,l (f32); attn_comb does the LSE merge.
__global__ __launch_bounds__(256,2) void attn_k(const u16* __restrict__ qkv,
    u16* __restrict__ apart, float* __restrict__ ml)
{
  __shared__ __attribute__((aligned(16))) u16 Ks[2][64*64];  // [key][d], 128B rows, swz
  __shared__ __attribute__((aligned(16))) u16 Vt[64*64];     // [d][key], 128B rows, swz
  int tid=threadIdx.x, wid=tid>>6, lane=tid&63, ql=lane&31, hl=lane>>5;
  int bid = blockIdx.x;
  int hb = bid & 31, z = (bid>>5)&1, qt = bid >> 6;
  int h = hb & 15, b = hb >> 4;
  int q0 = (qt<<7) + (wid<<5);
  size_t kbase = ((size_t)(b*SB + (z<<10)))*3072 + 1024 + (h<<6);
  size_t vbase = kbase + 1024;

  s16x8 bq[4];
  {
    size_t qrow = ((size_t)b*SB + q0 + ql)*3072 + (h<<6);
    #pragma unroll
    for (int dc=0; dc<4; ++dc) bq[dc] = *(const s16x8*)(qkv + qrow + (dc<<4) + (hl<<3));
  }

  int kp = tid & 31, dgrp = tid >> 5;

  #pragma unroll
  for (int i=0;i<2;i++){
    int chunk = (wid<<1)+i;
    int p = (chunk<<10) + (lane<<4);
    int row = p>>7;
    int colb = (p&127) ^ ((row&7)<<4);
    glds16(qkv + kbase + (size_t)row*3072 + (colb>>1), Ks[0] + (chunk<<9));
  }
  s16x8 v0 = *(const s16x8*)(qkv + vbase + (size_t)(2*kp)*3072 + (dgrp<<3));
  s16x8 v1 = *(const s16x8*)(qkv + vbase + (size_t)(2*kp+1)*3072 + (dgrp<<3));

  float m_r = -1e30f, l_r = 0.f;
  f32x16 acc[2] = {};
  int cur = 0;
  for (int kt=0; kt<16; ++kt){
    __syncthreads();
    #pragma unroll
    for (int i=0;i<8;i++){
      int d = (dgrp<<3)+i;
      u32 val = ((u32)(u16)v0[i]) | (((u32)(u16)v1[i])<<16);
      *(u32*)((char*)Vt + (d<<7) + ((kp<<2) ^ ((d&7)<<4))) = val;
    }
    __syncthreads();
    if (kt+1 < 16){
      int k0n = (kt+1)<<6;
      #pragma unroll
      for (int i=0;i<2;i++){
        int chunk = (wid<<1)+i;
        int p = (chunk<<10) + (lane<<4);
        int row = p>>7;
        int colb = (p&127) ^ ((row&7)<<4);
        glds16(qkv + kbase + (size_t)(k0n+row)*3072 + (colb>>1), Ks[cur^1] + (chunk<<9));
      }
      v0 = *(const s16x8*)(qkv + vbase + (size_t)(k0n + 2*kp)*3072 + (dgrp<<3));
      v1 = *(const s16x8*)(qkv + vbase + (size_t)(k0n + 2*kp+1)*3072 + (dgrp<<3));
    }
    const char* Kb = (const char*)Ks[cur];
    f32x16 s0 = {}, s1 = {};
    #pragma unroll
    for (int dc=0; dc<4; ++dc){
      int cb = ((dc<<4) + (hl<<3)) << 1;
      {
        int row = ql;
        s16x8 ka = *(const s16x8*)(Kb + (row<<7) + (cb ^ ((row&7)<<4)));
        s0 = __builtin_amdgcn_mfma_f32_32x32x16_bf16(ka, bq[dc], s0, 0,0,0);
      }
      {
        int row = 32+ql;
        s16x8 ka = *(const s16x8*)(Kb + (row<<7) + (cb ^ ((row&7)<<4)));
        s1 = __builtin_amdgcn_mfma_f32_32x32x16_bf16(ka, bq[dc], s1, 0,0,0);
      }
    }
    // online softmax in exp2 domain (q lane-local; only cross-op is lane^32)
    float mt = s0[0];
    #pragma unroll
    for (int r=1;r<16;r++) mt = fmaxf(mt, s0[r]);
    #pragma unroll
    for (int r=0;r<16;r++) mt = fmaxf(mt, s1[r]);
    mt = fmaxf(mt, __shfl_xor(mt, 32));
    float mn = fmaxf(m_r, mt);
    float al = exp2f(m_r - mn);
    m_r = mn;
    float sm = 0.f;
    #pragma unroll
    for (int r=0;r<16;r++){ s0[r] = exp2f(s0[r]-mn); sm += s0[r]; }
    #pragma unroll
    for (int r=0;r<16;r++){ s1[r] = exp2f(s1[r]-mn); sm += s1[r]; }
    sm += __shfl_xor(sm, 32);
    l_r = l_r*al + sm;
    acc[0] = acc[0]*al;
    acc[1] = acc[1]*al;
    s16x8 pb[4];
    #pragma unroll
    for (int c=0;c<4;c++){
      u32x4 fr;
      #pragma unroll
      for (int bp=0; bp<2; ++bp){
        int ba = 8*(c&1);
        float alo, ahi, blo, bhi;
        if (c>>1){ alo=s1[ba+2*bp]; ahi=s1[ba+2*bp+1]; blo=s1[ba+4+2*bp]; bhi=s1[ba+4+2*bp+1]; }
        else     { alo=s0[ba+2*bp]; ahi=s0[ba+2*bp+1]; blo=s0[ba+4+2*bp]; bhi=s0[ba+4+2*bp+1]; }
        u32 A = pkbf(alo, ahi);
        u32 B = pkbf(blo, bhi);
        s32x2 swp = __builtin_amdgcn_permlane32_swap((int)A, (int)B, false, false);
        fr[bp]   = (u32)swp[0];
        fr[bp+2] = (u32)swp[1];
      }
      pb[c] = __builtin_bit_cast(s16x8, fr);
    }
    #pragma unroll
    for (int dh=0; dh<2; ++dh){
      #pragma unroll
      for (int c=0;c<4;c++){
        int d = (dh<<5) + ql;
        s16x8 vf = *(const s16x8*)((const char*)Vt + (d<<7) + ((((c<<5)+(hl<<4))) ^ ((d&7)<<4)));
        acc[dh] = __builtin_amdgcn_mfma_f32_32x32x16_bf16(vf, pb[c], acc[dh], 0,0,0);
      }
    }
    cur ^= 1;
  }
  // per-(q,h) m,l
  if (hl == 0){
    size_t tok = (size_t)b*SB + q0 + ql;
    size_t idx = (((size_t)z*NTOK + tok)*NH + h)*2;
    ml[idx] = m_r; ml[idx+1] = l_r;
  }
  __syncthreads();
  // store UNNORMALIZED A via per-wave LDS transpose, coalesced bf16
  u16* Os = (u16*)Ks[0] + (wid<<11);
  #pragma unroll
  for (int dh=0; dh<2; ++dh)
    #pragma unroll
    for (int a=0;a<4;a++)
      #pragma unroll
      for (int bp=0;bp<2;bp++){
        u32 w = pkbf(acc[dh][4*a+2*bp], acc[dh][4*a+2*bp+1]);
        int d2 = (dh<<5) + (a<<3) + (hl<<2) + (bp<<1);
        *(u32*)((char*)Os + (ql<<7) + (((d2<<1)) ^ ((ql&7)<<4))) = w;
      }
  int rw = lane>>1, half = lane&1;
  size_t gb = ((size_t)z*NTOK + (size_t)b*SB + q0 + rw)*DD + (h<<6) + (half<<5);
  #pragma unroll
  for (int j=0;j<4;j++){
    s16x8 o = *(const s16x8*)((const char*)Os + (rw<<7) + ((((half<<6)+(j<<4))) ^ ((rw&7)<<4)));
    *(s16x8*)(apart + gb + (j<<3)) = o;
  }
}

// LSE merge of the two KV halves -> ctx bf16
__global__ __launch_bounds__(256) void attn_comb(const u16* __restrict__ apart,
    const float* __restrict__ ml, u16* __restrict__ ctx)
{
  int tok = blockIdx.x, tid = threadIdx.x;
  int h = tid >> 4;
  size_t i0 = (((size_t)tok)*NH + h)*2;
  size_t i1 = (((size_t)NTOK + tok)*NH + h)*2;
  float m0 = ml[i0], l0 = ml[i0+1];
  float m1 = ml[i1], l1 = ml[i1+1];
  float m = fmaxf(m0, m1);
  float w0 = exp2f(m0 - m), w1 = exp2f(m1 - m);
  float inv = 1.f / (w0*l0 + w1*l1);
  w0 *= inv; w1 *= inv;
  size_t e = (size_t)tok*DD + (tid<<2);
  ushort4 a0 = *(const ushort4*)(apart + e);
  ushort4 a1 = *(const ushort4*)(apart + (size_t)NTOK*DD + e);
  ushort4 o;
  o.x = f2b(b2f(a0.x)*w0 + b2f(a1.x)*w1);
  o.y = f2b(b2f(a0.y)*w0 + b2f(a1.y)*w1);
  o.z = f2b(b2f(a0.z)*w0 + b2f(a1.z)*w1);
  o.w = f2b(b2f(a0.w)*w0 + b2f(a1.w)*w1);
  *(ushort4*)(ctx + e) = o;
}

// ---------------- launch ----------------
extern "C" void kernel_launch(void* const* d_in, const int* in_sizes, int n_in,
                              void* d_out, int out_size, void* d_ws, size_t ws_size,
                              hipStream_t stream)
{
  (void)in_sizes; (void)n_in; (void)out_size; (void)ws_size;
  const float* x       = (const float*)d_in[0];
  const float* ffnmask = (const float*)d_in[2];
  const float* conv1_w = (const float*)d_in[3];
  const float* conv1_b = (const float*)d_in[4];
  const float* ln1_g   = (const float*)d_in[5];
  const float* ln1_b   = (const float*)d_in[6];
  const float* conv2_w = (const float*)d_in[7];
  const float* conv2_b = (const float*)d_in[8];
  const float* ln2_g   = (const float*)d_in[9];
  const float* ln2_b   = (const float*)d_in[10];
  const float* lnA_g   = (const float*)d_in[11];
  const float* lnA_b   = (const float*)d_in[12];
  const float* Wq      = (const float*)d_in[13];
  const float* Wk      = (const float*)d_in[14];
  const float* Wv      = (const float*)d_in[15];
  const float* Wo      = (const float*)d_in[16];
  const float* lnF_g   = (const float*)d_in[17];
  const float* lnF_b   = (const float*)d_in[18];
  const float* W1      = (const float*)d_in[19];
  const float* b1      = (const float*)d_in[20];
  const float* W2      = (const float*)d_in[21];
  const float* b2      = (const float*)d_in[22];
  float* out = (float*)d_out;
  char* ws = (char*)d_ws;
  u16*  cw1    = (u16*)(ws + OFF_CW1);
  u16*  cw2    = (u16*)(ws + OFF_CW2);
  u16*  wqkv   = (u16*)(ws + OFF_WQKV);
  u16*  wo     = (u16*)(ws + OFF_WO);
  u16*  w1p    = (u16*)(ws + OFF_W1);
  u16*  w2p    = (u16*)(ws + OFF_W2);
  float* pre   = (float*)(ws + OFF_PRE);
  u16*  apart  = (u16*)(ws + OFF_APART);
  u16*  qkvb   = (u16*)(ws + OFF_QKVB);
  u16*  interb = (u16*)(ws + OFF_INTER);
  u16*  xpad   = (u16*)(ws + OFF_XPAD);
  u16*  lnfb   = (u16*)(ws + OFF_LNF);
  u16*  hpad   = (u16*)(ws + OFF_HPAD);
  u16*  ctxb   = (u16*)(ws + OFF_CTX);
  float* inputs= (float*)(ws + OFF_INPUTS);
  u16*  xnb    = (u16*)(ws + OFF_XN);
  float* mlbuf = (float*)(ws + OFF_ML);

  // weight packs (bf16); q-scale (1/8)*log2e folded into Wq (exp2-domain softmax)
  pack_convw_k<<<12288, 256, 0, stream>>>(conv1_w, cw1);
  pack_convw_k<<<12288, 256, 0, stream>>>(conv2_w, cw2);
  pack_scale_k<<<4096, 256, 0, stream>>>(Wq, wqkv,             1024*1024, 0.125f*1.4426950408889634f);
  pack_scale_k<<<4096, 256, 0, stream>>>(Wk, wqkv + (1u<<20),  1024*1024, 1.f);
  pack_scale_k<<<4096, 256, 0, stream>>>(Wv, wqkv + (2u<<20),  1024*1024, 1.f);
  pack_scale_k<<<4096, 256, 0, stream>>>(Wo, wo,               1024*1024, 1.f);
  pack_scale_k<<<16384, 256, 0, stream>>>(W1, w1p, 4096*1024, 1.f);
  pack_scale_k<<<16384, 256, 0, stream>>>(W2, w2p, 4096*1024, 1.f);
  pad_x_k<<<NB*SP, 256, 0, stream>>>(x, xpad);

  // conv1 -> relu -> LN1 (padded bf16 for conv2)
  conv_gemm<<<dim3(32,8), 512, 0, stream>>>(xpad, cw1, pre);
  ln_k<0><<<NB*SP, 256, 0, stream>>>(pre, conv1_b, ln1_g, ln1_b, nullptr, nullptr, hpad);
  // conv2 -> relu -> LN2 -> +x => inputs (f32)
  conv_gemm<<<dim3(32,8), 512, 0, stream>>>(hpad, cw2, pre);
  ln_k<1><<<NTOK, 256, 0, stream>>>(pre, conv2_b, ln2_g, ln2_b, x, inputs, nullptr);
  // lnA -> xn (bf16)
  ln_k<2><<<NTOK, 256, 0, stream>>>(inputs, nullptr, lnA_g, lnA_b, nullptr, nullptr, xnb);
  // fused QKV projection (8-phase 256^2)
  gemm8<16><<<dim3(16,12), 512, 0, stream>>>(xnb, wqkv, 3072, 1024, nullptr, nullptr, qkvb);
  // flash attention, KV-split z=2 + LSE combine
  attn_k<<<1024, 256, 0, stream>>>(qkvb, apart, mlbuf);
  attn_comb<<<NTOK, 256, 0, stream>>>(apart, mlbuf, ctxb);
  // out = ctx @ Wo^T + inputs
  gemm_wo<<<dim3(32,8), 512, 0, stream>>>(ctxb, wo, inputs, out);
  // lnF -> bf16
  ln_k<2><<<NTOK, 256, 0, stream>>>(out, nullptr, lnF_g, lnF_b, nullptr, nullptr, lnfb);
  // inter = relu(lnF @ W1^T + b1) (8-phase 256^2)
  gemm8<19><<<dim3(16,16), 512, 0, stream>>>(lnfb, w1p, 4096, 1024, b1, nullptr, interb);
  // final = (inter @ W2^T + b2)*mask + out
  gemm_f2<<<dim3(32,8), 512, 0, stream>>>(interb, w2p, b2, ffnmask, out);
}

// Round 7
// 400.566 us; speedup vs baseline: 1.1181x; 1.0277x over previous
//
#include <hip/hip_runtime.h>
#include <hip/hip_bf16.h>
#include <cstdint>
#include <cstddef>

// TransformerEncoderLayer: B=2 S=2048 D=1024 H=16 DH=64 DFF=4096, fp32 in/out.
// Round 6: (a) revert attn KV-split (r5 regression) -> r3 structure + exp2
// domain + T13 defer-max + v_perm V-pack. (b) gemm8 schedule fixed to the
// m201 template: stage order gives >=5-phase lead, per-phase vmcnt(8),
// sched_barrier(0) removed.

#define SB 2048
#define DD 1024
#define NB 2
#define NH 16
#define DFF_ 4096
#define NTOK (NB*SB)   // 4096
#define SP (SB+2)      // 2050 (padded rows for conv halo)

typedef unsigned short u16;
typedef unsigned int u32;
typedef float f32x4 __attribute__((ext_vector_type(4)));
typedef float f32x16 __attribute__((ext_vector_type(16)));
typedef short s16x8 __attribute__((ext_vector_type(8)));
typedef int s32x2 __attribute__((ext_vector_type(2)));
typedef u32 u32x4 __attribute__((ext_vector_type(4)));

__device__ __forceinline__ u16 f2b(float f){
  uint32_t u = __builtin_bit_cast(uint32_t, f);
  return (u16)((u + 0x7fffu + ((u >> 16) & 1u)) >> 16);  // RNE
}
__device__ __forceinline__ u32 pkbf(float lo, float hi){
  u32 r;
  asm("v_cvt_pk_bf16_f32 %0, %1, %2" : "=v"(r) : "v"(lo), "v"(hi));
  return r;
}

// ---------------- workspace layout (bytes) ----------------
constexpr size_t OFF_CW1   = 0;                                     // 3x1024x1024 bf16
constexpr size_t OFF_CW2   = OFF_CW1 + 3ull*1024*1024*2;
constexpr size_t OFF_WQKV  = OFF_CW2 + 3ull*1024*1024*2;            // 3072x1024 bf16 (q scaled log2e/8)
constexpr size_t OFF_WO    = OFF_WQKV + 3072ull*1024*2;
constexpr size_t OFF_W1    = OFF_WO + 1024ull*1024*2;
constexpr size_t OFF_W2    = OFF_W1 + 4096ull*1024*2;
constexpr size_t OFF_PRE   = OFF_W2 + 4096ull*1024*2;               // f32 4096x1024
constexpr size_t OFF_QKVB  = OFF_PRE + (size_t)NTOK*1024*4;         // bf16 4096x3072
constexpr size_t OFF_INTER = OFF_PRE;                               // alias: bf16 4096x4096
constexpr size_t OFF_XPAD  = OFF_QKVB + (size_t)NTOK*3072*2;        // bf16 2x2050x1024
constexpr size_t OFF_LNF   = OFF_XPAD;                              // alias
constexpr size_t OFF_HPAD  = OFF_XPAD + (size_t)NB*SP*1024*2;       // bf16 2x2050x1024
constexpr size_t OFF_CTX   = OFF_HPAD;                              // alias
constexpr size_t OFF_INPUTS= OFF_HPAD + (size_t)NB*SP*1024*2;       // f32 4096x1024
constexpr size_t OFF_XN    = OFF_INPUTS + (size_t)NTOK*1024*4;      // bf16 4096x1024

// ---------------- pack kernels ----------------
__global__ void pack_scale_k(const float* __restrict__ in, u16* __restrict__ out, int n, float scale){
  int i = blockIdx.x*256 + threadIdx.x;
  if (i < n) out[i] = f2b(in[i]*scale);
}

// w[o][i][t] (D,D,3) -> out[t][o][i] bf16
__global__ void pack_convw_k(const float* __restrict__ w, u16* __restrict__ out){
  int i = blockIdx.x*256 + threadIdx.x;   // over 3*1024*1024
  int t = i >> 20;
  int rem = i & 1048575;
  int o = rem >> 10;
  int c = rem & 1023;
  out[i] = f2b(w[o*3072 + c*3 + t]);
}

// x f32 (B,S,D) -> xpad bf16 (B,S+2,D), zero halo rows
__global__ void pad_x_k(const float* __restrict__ x, u16* __restrict__ xp){
  int row = blockIdx.x;  // 0..NB*SP-1
  int tid = threadIdx.x;
  int b = row / SP, s = row - b*SP;
  ushort4 st;
  if (s == 0 || s == SP-1){ st.x=0; st.y=0; st.z=0; st.w=0; }
  else {
    float4 v = ((const float4*)(x + ((size_t)b*SB + s-1)*DD))[tid];
    st.x=f2b(v.x); st.y=f2b(v.y); st.z=f2b(v.z); st.w=f2b(v.w);
  }
  ((ushort4*)(xp + (size_t)row*DD))[tid] = st;
}

// ---------------- LayerNorm ----------------
template<int MODE>
__global__ __launch_bounds__(256) void ln_k(const float* __restrict__ in, const float* __restrict__ cb,
    const float* __restrict__ g, const float* __restrict__ be, const float* __restrict__ resid,
    float* __restrict__ outf, u16* __restrict__ outb)
{
  int row = blockIdx.x, tid = threadIdx.x;
  int inrow = row;
  if (MODE == 0){
    int b = row / SP, s = row - b*SP;
    if (s == 0 || s == SP-1){
      ushort4 z; z.x=0; z.y=0; z.z=0; z.w=0;
      ((ushort4*)(outb + (size_t)row*DD))[tid] = z;
      return;
    }
    inrow = b*SB + s - 1;
  }
  float4 v = ((const float4*)(in + (size_t)inrow*DD))[tid];
  if (MODE <= 1){
    float4 c = ((const float4*)cb)[tid];
    v.x = fmaxf(v.x + c.x, 0.f);
    v.y = fmaxf(v.y + c.y, 0.f);
    v.z = fmaxf(v.z + c.z, 0.f);
    v.w = fmaxf(v.w + c.w, 0.f);
  }
  float s1 = v.x+v.y+v.z+v.w;
  float s2 = v.x*v.x + v.y*v.y + v.z*v.z + v.w*v.w;
  #pragma unroll
  for (int d=32; d>=1; d>>=1){ s1 += __shfl_down(s1, d); s2 += __shfl_down(s2, d); }
  __shared__ float red[8];
  int wid = tid >> 6, lane = tid & 63;
  if (lane==0){ red[wid] = s1; red[4+wid] = s2; }
  __syncthreads();
  s1 = red[0]+red[1]+red[2]+red[3];
  s2 = red[4]+red[5]+red[6]+red[7];
  float mu = s1 * (1.f/DD);
  float var = s2 * (1.f/DD) - mu*mu;
  float rs = rsqrtf(var + 1e-6f);
  float4 gg = ((const float4*)g)[tid];
  float4 bb = ((const float4*)be)[tid];
  float o0 = (v.x-mu)*rs*gg.x + bb.x;
  float o1 = (v.y-mu)*rs*gg.y + bb.y;
  float o2 = (v.z-mu)*rs*gg.z + bb.z;
  float o3 = (v.w-mu)*rs*gg.w + bb.w;
  if (MODE == 1){
    float4 rr = ((const float4*)(resid + (size_t)inrow*DD))[tid];
    float4 o; o.x=o0+rr.x; o.y=o1+rr.y; o.z=o2+rr.z; o.w=o3+rr.w;
    ((float4*)(outf + (size_t)inrow*DD))[tid] = o;
  } else {
    ushort4 st; st.x=f2b(o0); st.y=f2b(o1); st.z=f2b(o2); st.w=f2b(o3);
    ((ushort4*)(outb + (size_t)row*DD))[tid] = st;
  }
}

// ---------------- shared GEMM helpers ----------------
__device__ __forceinline__ void glds16(const u16* g, u16* l){
  __builtin_amdgcn_global_load_lds((const __attribute__((address_space(1))) void*)g,
                                   (__attribute__((address_space(3))) void*)l, 16, 0, 0);
}

// stage a [128 rows][64 cols] bf16 tile (16KB) with 512 threads, XOR-swizzled
// via pre-swizzled GLOBAL source (global_load_lds writes linearly).
__device__ __forceinline__ void stage_tile8(const u16* __restrict__ src, int strideK, u16* lds, int wid, int lane){
  #pragma unroll
  for (int i=0;i<2;i++){
    int chunk = (wid<<1) + i;            // 16 chunks x 1KB
    int p = (chunk<<10) + (lane<<4);     // linear LDS byte this lane fills
    int row = p >> 7;
    int clg = (p & 127) ^ ((row & 7) << 4);
    glds16(src + (size_t)row*strideK + (clg>>1), lds + (chunk<<9));
  }
}

__device__ __forceinline__ s16x8 ldsrd(const u16* slot, int r, int ks, int hi){
  int off = (r<<7) + (((ks<<6)+(hi<<4)) ^ ((r&7)<<4));
  return *(const s16x8*)((const char*)slot + off);
}

__device__ __forceinline__ void kstep_mfma8(const u16* As, const u16* Bs, int wr, int wc, int lr, int hi, f32x4 acc[4][2]){
  s16x8 af[2][4], bf[2][2];
  #pragma unroll
  for (int ks=0; ks<2; ++ks){
    #pragma unroll
    for (int m=0;m<4;m++) af[ks][m] = ldsrd(As, (wr<<6)+(m<<4)+lr, ks, hi);
    #pragma unroll
    for (int n=0;n<2;n++) bf[ks][n] = ldsrd(Bs, (wc<<5)+(n<<4)+lr, ks, hi);
  }
  #pragma unroll
  for (int ks=0;ks<2;++ks)
    #pragma unroll
    for (int m=0;m<4;m++)
      #pragma unroll
      for (int n=0;n<2;n++)
        acc[m][n] = __builtin_amdgcn_mfma_f32_16x16x32_bf16(af[ks][m], bf[ks][n], acc[m][n], 0,0,0);
}

// ---------------- 8-phase 256x256 GEMM (C = A @ B^T), plain-store ----------
// m201-faithful: per phase {ds-read frags, stage 1 half-tile (2 glds),
// vmcnt(8), barrier, lgkmcnt(0), setprio(1), 16 MFMA, setprio(0), barrier}.
// Stage order chosen so every slot has >=5-phase stage->first-read lead:
//   prologue: Aa0 Ba0 Bb0 Ab0 Aa1 Ba1
//   loop:     ph1..8 stage Bb(t1) Ab(t1) Aa(t2) Ba(t2) Bb(t2) Ab(t2) Aa(t3) Ba(t3)
// (verified: at each phase end vmcnt(8) keeps the newest 4 stages; all reads
// target slots staged >=5 phases back -> landed.)
__device__ __forceinline__ void rdA8(const u16* sA, int wr, int lr, int hi, s16x8 af[2][4]){
  #pragma unroll
  for (int ks=0;ks<2;ks++)
    #pragma unroll
    for (int m=0;m<4;m++)
      af[ks][m] = ldsrd(sA, (wr<<6)+(m<<4)+lr, ks, hi);
}
__device__ __forceinline__ void rdB8(const u16* sB, int wc, int lr, int hi, s16x8 bf[2][2]){
  #pragma unroll
  for (int ks=0;ks<2;ks++)
    #pragma unroll
    for (int n=0;n<2;n++)
      bf[ks][n] = ldsrd(sB, (wc<<5)+(n<<4)+lr, ks, hi);
}
__device__ __forceinline__ void mm16(const s16x8 af[2][4], const s16x8 bf[2][2], f32x4 a[4][2]){
  #pragma unroll
  for (int ks=0;ks<2;ks++)
    #pragma unroll
    for (int m=0;m<4;m++)
      #pragma unroll
      for (int n=0;n<2;n++)
        a[m][n] = __builtin_amdgcn_mfma_f32_16x16x32_bf16(af[ks][m], bf[ks][n], a[m][n], 0,0,0);
}

template<int EPI>
__global__ __launch_bounds__(512,2) void gemm8(const u16* __restrict__ A, const u16* __restrict__ Bm,
    int N, int K, const float* __restrict__ bias,
    float* __restrict__ Cf, u16* __restrict__ Cb)
{
  __shared__ __attribute__((aligned(16))) u16 Lsh[8*8192];   // 8 x 16KB half-slots
  int tid=threadIdx.x, wid=tid>>6, lane=tid&63, lr=lane&15, hi=lane>>4;
  int wr=wid>>2, wc=wid&3;
  int m0=blockIdx.x<<8, n0=blockIdx.y<<8;
  const u16* Abase = A + (size_t)m0*K;
  const u16* Bbase = Bm + (size_t)n0*K;
  int NT = K >> 6;
  f32x4 acc[2][2][4][2] = {};
  s16x8 af[2][4], bf[2][2];

#define LB(isB,half,par) (Lsh + ((((isB)<<2)|((half)<<1)|(par))<<13))
  // prologue stage order: Aa0 Ba0 Bb0 Ab0 Aa1 Ba1  (then vmcnt(8) drains Aa0,Ba0)
  stage_tile8(Abase,                   K, LB(0,0,0), wid, lane);
  stage_tile8(Bbase,                   K, LB(1,0,0), wid, lane);
  stage_tile8(Bbase + (size_t)128*K,   K, LB(1,1,0), wid, lane);
  stage_tile8(Abase + (size_t)128*K,   K, LB(0,1,0), wid, lane);
  stage_tile8(Abase + 64,              K, LB(0,0,1), wid, lane);
  stage_tile8(Bbase + 64,              K, LB(1,0,1), wid, lane);
  asm volatile("s_waitcnt vmcnt(8)" ::: "memory");
  __builtin_amdgcn_s_barrier();

#define PH(h_, g_, p_, doA, sIsB, sHalf, sTile) do{ \
    if (doA) rdA8(LB(0,h_,p_), wr, lr, hi, af); \
    rdB8(LB(1,g_,p_), wc, lr, hi, bf); \
    { int tt=(sTile); int tc = (tt<NT)? tt : (NT-2+(tt&1)); \
      const u16* ss = ((sIsB)? Bbase : Abase) + (size_t)((sHalf)*128)*K + ((size_t)tc<<6); \
      stage_tile8(ss, K, LB(sIsB,sHalf,tc&1), wid, lane); } \
    asm volatile("s_waitcnt vmcnt(8)" ::: "memory"); \
    __builtin_amdgcn_s_barrier(); \
    asm volatile("s_waitcnt lgkmcnt(0)" ::: "memory"); \
    __builtin_amdgcn_s_setprio(1); \
    mm16(af, bf, acc[h_][g_]); \
    __builtin_amdgcn_s_setprio(0); \
    __builtin_amdgcn_s_barrier(); \
  }while(0)

  int half = NT>>1;
  for (int i=0; i<half; ++i){
    int t1 = 2*i+1, t2 = 2*i+2, t3 = 2*i+3;
    PH(0,0, 0, true,  1,1, t1);   // compute q(0,0) tile 2i;   stage Bb(t1)
    PH(0,1, 0, false, 0,1, t1);   // q(0,1);                   stage Ab(t1)
    PH(1,0, 0, true,  0,0, t2);   // q(1,0);                   stage Aa(t2)
    PH(1,1, 0, false, 1,0, t2);   // q(1,1);                   stage Ba(t2)
    PH(0,0, 1, true,  1,1, t2);   // tile 2i+1 q(0,0);         stage Bb(t2)
    PH(0,1, 1, false, 0,1, t2);   //                           stage Ab(t2)
    PH(1,0, 1, true,  0,0, t3);   //                           stage Aa(t3)
    PH(1,1, 1, false, 1,0, t3);   //                           stage Ba(t3)
  }
#undef PH
#undef LB

  #pragma unroll
  for (int h=0;h<2;h++)
    #pragma unroll
    for (int m=0;m<4;m++)
      #pragma unroll
      for (int r=0;r<4;r++){
        int row = m0 + (h<<7) + (wr<<6) + (m<<4) + (hi<<2) + r;
        #pragma unroll
        for (int g=0;g<2;g++)
          #pragma unroll
          for (int n=0;n<2;n++){
            int col = n0 + (g<<7) + (wc<<5) + (n<<4) + lr;
            float v = acc[h][g][m][n][r];
            if (EPI&1) v += bias[col];
            if (EPI&2) v = fmaxf(v, 0.f);
            if (EPI&16) Cb[(size_t)row*N + col] = f2b(v);
            else Cf[(size_t)row*N + col] = v;
          }
      }
}

// ---------------- 2-phase 128x128 GEMMs ----------------
// Wo: C = A@B^T + resid (f32 out)
__global__ __launch_bounds__(512,4) void gemm_wo(const u16* __restrict__ A, const u16* __restrict__ Bm,
    const float* __restrict__ resid, float* __restrict__ Cf)
{
  __shared__ __attribute__((aligned(16))) u16 As[2][128*64];
  __shared__ __attribute__((aligned(16))) u16 Bs[2][128*64];
  const int N = 1024, K = 1024;
  int tid=threadIdx.x, wid=tid>>6, lane=tid&63, lr=lane&15, hi=lane>>4;
  int wr=wid>>2, wc=wid&3;
  int m0=blockIdx.x<<7, n0=blockIdx.y<<7;
  f32x4 acc[4][2] = {};
  const u16* Ab = A + (size_t)m0*K;
  const u16* Bb = Bm + (size_t)n0*K;
  int nk = K >> 6;
  stage_tile8(Ab, K, As[0], wid, lane);
  stage_tile8(Bb, K, Bs[0], wid, lane);
  __syncthreads();
  int cur = 0;
  for (int kt=0; kt<nk; ++kt){
    if (kt+1 < nk){
      stage_tile8(Ab + ((kt+1)<<6), K, As[cur^1], wid, lane);
      stage_tile8(Bb + ((kt+1)<<6), K, Bs[cur^1], wid, lane);
    }
    kstep_mfma8(As[cur], Bs[cur], wr, wc, lr, hi, acc);
    __syncthreads();
    cur ^= 1;
  }
  #pragma unroll
  for (int m=0;m<4;m++)
    #pragma unroll
    for (int r=0;r<4;r++){
      int row = m0 + (wr<<6) + (m<<4) + (hi<<2) + r;
      #pragma unroll
      for (int n=0;n<2;n++){
        int col = n0 + (wc<<5) + (n<<4) + lr;
        Cf[(size_t)row*N + col] = acc[m][n][r] + resid[(size_t)row*N + col];
      }
    }
}

// FFN2: out = (A@B^T + b2)*mask[row] + out  (K=4096, f32 in-place)
__global__ __launch_bounds__(512,4) void gemm_f2(const u16* __restrict__ A, const u16* __restrict__ Bm,
    const float* __restrict__ bias, const float* __restrict__ mask, float* __restrict__ Cf)
{
  __shared__ __attribute__((aligned(16))) u16 As[2][128*64];
  __shared__ __attribute__((aligned(16))) u16 Bs[2][128*64];
  const int N = 1024, K = 4096;
  int tid=threadIdx.x, wid=tid>>6, lane=tid&63, lr=lane&15, hi=lane>>4;
  int wr=wid>>2, wc=wid&3;
  int m0=blockIdx.x<<7, n0=blockIdx.y<<7;
  f32x4 acc[4][2] = {};
  const u16* Ab = A + (size_t)m0*K;
  const u16* Bb = Bm + (size_t)n0*K;
  int nk = K >> 6;
  stage_tile8(Ab, K, As[0], wid, lane);
  stage_tile8(Bb, K, Bs[0], wid, lane);
  __syncthreads();
  int cur = 0;
  for (int kt=0; kt<nk; ++kt){
    if (kt+1 < nk){
      stage_tile8(Ab + ((kt+1)<<6), K, As[cur^1], wid, lane);
      stage_tile8(Bb + ((kt+1)<<6), K, Bs[cur^1], wid, lane);
    }
    kstep_mfma8(As[cur], Bs[cur], wr, wc, lr, hi, acc);
    __syncthreads();
    cur ^= 1;
  }
  #pragma unroll
  for (int m=0;m<4;m++)
    #pragma unroll
    for (int r=0;r<4;r++){
      int row = m0 + (wr<<6) + (m<<4) + (hi<<2) + r;
      float rm = mask[row];
      #pragma unroll
      for (int n=0;n<2;n++){
        int col = n0 + (wc<<5) + (n<<4) + lr;
        float v = (acc[m][n][r] + bias[col])*rm + Cf[(size_t)row*N + col];
        Cf[(size_t)row*N + col] = v;
      }
    }
}

// conv as GEMM over padded activations, taps flattened (2-phase, plain f32 out)
__global__ __launch_bounds__(512,4) void conv_gemm(const u16* __restrict__ xp, const u16* __restrict__ W3,
    float* __restrict__ Cf)
{
  __shared__ __attribute__((aligned(16))) u16 As[2][128*64];
  __shared__ __attribute__((aligned(16))) u16 Bs[2][128*64];
  int tid=threadIdx.x, wid=tid>>6, lane=tid&63, lr=lane&15, hi=lane>>4;
  int wr=wid>>2, wc=wid&3;
  int m0=blockIdx.x<<7, n0=blockIdx.y<<7;
  int bb = m0 >> 11, ss = m0 & 2047;
  f32x4 acc[4][2] = {};
  const u16* ab0 = xp + ((size_t)bb*SP + ss)*DD;
  const u16* bb0 = W3 + ((size_t)n0<<10);
  stage_tile8(ab0, DD, As[0], wid, lane);
  stage_tile8(bb0, DD, Bs[0], wid, lane);
  __syncthreads();
  int cur = 0;
  for (int idx=0; idx<48; ++idx){
    if (idx+1 < 48){
      int tap = (idx+1)>>4, kt = (idx+1)&15;
      stage_tile8(ab0 + (size_t)tap*DD + (kt<<6), DD, As[cur^1], wid, lane);
      stage_tile8(bb0 + ((size_t)tap<<20) + (kt<<6), DD, Bs[cur^1], wid, lane);
    }
    kstep_mfma8(As[cur], Bs[cur], wr, wc, lr, hi, acc);
    __syncthreads();
    cur ^= 1;
  }
  #pragma unroll
  for (int m=0;m<4;m++)
    #pragma unroll
    for (int r=0;r<4;r++){
      int row = m0 + (wr<<6) + (m<<4) + (hi<<2) + r;
      #pragma unroll
      for (int n=0;n<2;n++){
        int col = n0 + (wc<<5) + (n<<4) + lr;
        Cf[(size_t)row*DD + col] = acc[m][n][r];
      }
    }
}

// ---------------- flash attention (r3 structure + exp2 + defer-max) --------
// qkv: [NTOK][3072] bf16 = [q k v], q pre-scaled by log2e/8 (exp2 domain).
// Grid 512: hb=bid&31 (h,b), qt=bid>>5 (XCD locality). 4 waves, wave owns
// 32 q rows. KV tile 64 keys, 32 iters. Swapped QK^T + swapped PV => q is
// lane-local everywhere; P frags via cvt_pk + permlane32_swap; T13 defer-max.
__global__ __launch_bounds__(256,2) void attn_k(const u16* __restrict__ qkv, u16* __restrict__ ctx)
{
  __shared__ __attribute__((aligned(16))) u16 Ks[2][64*64];  // [key][d], 128B rows, swz
  __shared__ __attribute__((aligned(16))) u16 Vt[64*64];     // [d][key], 128B rows, swz
  int tid=threadIdx.x, wid=tid>>6, lane=tid&63, ql=lane&31, hl=lane>>5;
  int bid = blockIdx.x;
  int hb = bid & 31, qt = bid >> 5;
  int h = hb & 15, b = hb >> 4;
  int q0 = (qt<<7) + (wid<<5);
  size_t kbase = ((size_t)b*SB)*3072 + 1024 + (h<<6);
  size_t vbase = kbase + 1024;

  s16x8 bq[4];
  {
    size_t qrow = ((size_t)b*SB + q0 + ql)*3072 + (h<<6);
    #pragma unroll
    for (int dc=0; dc<4; ++dc) bq[dc] = *(const s16x8*)(qkv + qrow + (dc<<4) + (hl<<3));
  }

  int kp = tid & 31, dgrp = tid >> 5;

  #pragma unroll
  for (int i=0;i<2;i++){
    int chunk = (wid<<1)+i;
    int p = (chunk<<10) + (lane<<4);
    int row = p>>7;
    int colb = (p&127) ^ ((row&7)<<4);
    glds16(qkv + kbase + (size_t)row*3072 + (colb>>1), Ks[0] + (chunk<<9));
  }
  s16x8 v0 = *(const s16x8*)(qkv + vbase + (size_t)(2*kp)*3072 + (dgrp<<3));
  s16x8 v1 = *(const s16x8*)(qkv + vbase + (size_t)(2*kp+1)*3072 + (dgrp<<3));

  float m_r = -1e30f, l_r = 0.f;
  f32x16 acc[2] = {};
  int cur = 0;
  for (int kt=0; kt<32; ++kt){
    __syncthreads();
    // V transpose into Vt[d][key] via v_perm key-pair packing (2 lanes/bank)
    {
      u32x4 w0 = __builtin_bit_cast(u32x4, v0);
      u32x4 w1 = __builtin_bit_cast(u32x4, v1);
      #pragma unroll
      for (int w=0; w<4; ++w){
        u32 ve = __builtin_amdgcn_perm(w1[w], w0[w], 0x05040100u);  // d=2w
        u32 vo = __builtin_amdgcn_perm(w1[w], w0[w], 0x07060302u);  // d=2w+1
        int d0 = (dgrp<<3) + (w<<1);
        *(u32*)((char*)Vt + ((d0  )<<7) + ((kp<<2) ^ (((d0  )&7)<<4))) = ve;
        *(u32*)((char*)Vt + ((d0+1)<<7) + ((kp<<2) ^ (((d0+1)&7)<<4))) = vo;
      }
    }
    __syncthreads();
    if (kt+1 < 32){
      int k0n = (kt+1)<<6;
      #pragma unroll
      for (int i=0;i<2;i++){
        int chunk = (wid<<1)+i;
        int p = (chunk<<10) + (lane<<4);
        int row = p>>7;
        int colb = (p&127) ^ ((row&7)<<4);
        glds16(qkv + kbase + (size_t)(k0n+row)*3072 + (colb>>1), Ks[cur^1] + (chunk<<9));
      }
      v0 = *(const s16x8*)(qkv + vbase + (size_t)(k0n + 2*kp)*3072 + (dgrp<<3));
      v1 = *(const s16x8*)(qkv + vbase + (size_t)(k0n + 2*kp+1)*3072 + (dgrp<<3));
    }
    const char* Kb = (const char*)Ks[cur];
    f32x16 s0 = {}, s1 = {};
    #pragma unroll
    for (int dc=0; dc<4; ++dc){
      int cb = ((dc<<4) + (hl<<3)) << 1;
      {
        int row = ql;
        s16x8 ka = *(const s16x8*)(Kb + (row<<7) + (cb ^ ((row&7)<<4)));
        s0 = __builtin_amdgcn_mfma_f32_32x32x16_bf16(ka, bq[dc], s0, 0,0,0);
      }
      {
        int row = 32+ql;
        s16x8 ka = *(const s16x8*)(Kb + (row<<7) + (cb ^ ((row&7)<<4)));
        s1 = __builtin_amdgcn_mfma_f32_32x32x16_bf16(ka, bq[dc], s1, 0,0,0);
      }
    }
    // online softmax, exp2 domain, T13 defer-max (THR=8 -> P <= 256)
    float mt = s0[0];
    #pragma unroll
    for (int r=1;r<16;r++) mt = fmaxf(mt, s0[r]);
    #pragma unroll
    for (int r=0;r<16;r++) mt = fmaxf(mt, s1[r]);
    mt = fmaxf(mt, __shfl_xor(mt, 32));
    if (!__all(mt <= m_r + 8.f)){
      float mn = fmaxf(m_r, mt);
      float al = exp2f(m_r - mn);
      m_r = mn;
      l_r *= al;
      acc[0] = acc[0]*al;
      acc[1] = acc[1]*al;
    }
    float sm = 0.f;
    #pragma unroll
    for (int r=0;r<16;r++){ s0[r] = exp2f(s0[r]-m_r); sm += s0[r]; }
    #pragma unroll
    for (int r=0;r<16;r++){ s1[r] = exp2f(s1[r]-m_r); sm += s1[r]; }
    sm += __shfl_xor(sm, 32);
    l_r += sm;
    s16x8 pb[4];
    #pragma unroll
    for (int c=0;c<4;c++){
      u32x4 fr;
      #pragma unroll
      for (int bp=0; bp<2; ++bp){
        int ba = 8*(c&1);
        float alo, ahi, blo, bhi;
        if (c>>1){ alo=s1[ba+2*bp]; ahi=s1[ba+2*bp+1]; blo=s1[ba+4+2*bp]; bhi=s1[ba+4+2*bp+1]; }
        else     { alo=s0[ba+2*bp]; ahi=s0[ba+2*bp+1]; blo=s0[ba+4+2*bp]; bhi=s0[ba+4+2*bp+1]; }
        u32 A = pkbf(alo, ahi);
        u32 B = pkbf(blo, bhi);
        s32x2 swp = __builtin_amdgcn_permlane32_swap((int)A, (int)B, false, false);
        fr[bp]   = (u32)swp[0];
        fr[bp+2] = (u32)swp[1];
      }
      pb[c] = __builtin_bit_cast(s16x8, fr);
    }
    #pragma unroll
    for (int dh=0; dh<2; ++dh){
      #pragma unroll
      for (int c=0;c<4;c++){
        int d = (dh<<5) + ql;
        s16x8 vf = *(const s16x8*)((const char*)Vt + (d<<7) + ((((c<<5)+(hl<<4))) ^ ((d&7)<<4)));
        acc[dh] = __builtin_amdgcn_mfma_f32_32x32x16_bf16(vf, pb[c], acc[dh], 0,0,0);
      }
    }
    cur ^= 1;
  }
  __syncthreads();
  float inv = 1.f / l_r;
  u16* Os = (u16*)Ks[0] + (wid<<11);
  #pragma unroll
  for (int dh=0; dh<2; ++dh)
    #pragma unroll
    for (int a=0;a<4;a++)
      #pragma unroll
      for (int bp=0;bp<2;bp++){
        u32 w = pkbf(acc[dh][4*a+2*bp]*inv, acc[dh][4*a+2*bp+1]*inv);
        int d2 = (dh<<5) + (a<<3) + (hl<<2) + (bp<<1);
        *(u32*)((char*)Os + (ql<<7) + (((d2<<1)) ^ ((ql&7)<<4))) = w;
      }
  int rw = lane>>1, half = lane&1;
  size_t gb = ((size_t)b*SB + q0 + rw)*DD + (h<<6) + (half<<5);
  #pragma unroll
  for (int j=0;j<4;j++){
    s16x8 o = *(const s16x8*)((const char*)Os + (rw<<7) + ((((half<<6)+(j<<4))) ^ ((rw&7)<<4)));
    *(s16x8*)(ctx + gb + (j<<3)) = o;
  }
}

// ---------------- launch ----------------
extern "C" void kernel_launch(void* const* d_in, const int* in_sizes, int n_in,
                              void* d_out, int out_size, void* d_ws, size_t ws_size,
                              hipStream_t stream)
{
  (void)in_sizes; (void)n_in; (void)out_size; (void)ws_size;
  const float* x       = (const float*)d_in[0];
  const float* ffnmask = (const float*)d_in[2];
  const float* conv1_w = (const float*)d_in[3];
  const float* conv1_b = (const float*)d_in[4];
  const float* ln1_g   = (const float*)d_in[5];
  const float* ln1_b   = (const float*)d_in[6];
  const float* conv2_w = (const float*)d_in[7];
  const float* conv2_b = (const float*)d_in[8];
  const float* ln2_g   = (const float*)d_in[9];
  const float* ln2_b   = (const float*)d_in[10];
  const float* lnA_g   = (const float*)d_in[11];
  const float* lnA_b   = (const float*)d_in[12];
  const float* Wq      = (const float*)d_in[13];
  const float* Wk      = (const float*)d_in[14];
  const float* Wv      = (const float*)d_in[15];
  const float* Wo      = (const float*)d_in[16];
  const float* lnF_g   = (const float*)d_in[17];
  const float* lnF_b   = (const float*)d_in[18];
  const float* W1      = (const float*)d_in[19];
  const float* b1      = (const float*)d_in[20];
  const float* W2      = (const float*)d_in[21];
  const float* b2      = (const float*)d_in[22];
  float* out = (float*)d_out;
  char* ws = (char*)d_ws;
  u16*  cw1    = (u16*)(ws + OFF_CW1);
  u16*  cw2    = (u16*)(ws + OFF_CW2);
  u16*  wqkv   = (u16*)(ws + OFF_WQKV);
  u16*  wo     = (u16*)(ws + OFF_WO);
  u16*  w1p    = (u16*)(ws + OFF_W1);
  u16*  w2p    = (u16*)(ws + OFF_W2);
  float* pre   = (float*)(ws + OFF_PRE);
  u16*  qkvb   = (u16*)(ws + OFF_QKVB);
  u16*  interb = (u16*)(ws + OFF_INTER);
  u16*  xpad   = (u16*)(ws + OFF_XPAD);
  u16*  lnfb   = (u16*)(ws + OFF_LNF);
  u16*  hpad   = (u16*)(ws + OFF_HPAD);
  u16*  ctxb   = (u16*)(ws + OFF_CTX);
  float* inputs= (float*)(ws + OFF_INPUTS);
  u16*  xnb    = (u16*)(ws + OFF_XN);

  // weight packs (bf16); q-scale (1/8)*log2e folded into Wq (exp2-domain softmax)
  pack_convw_k<<<12288, 256, 0, stream>>>(conv1_w, cw1);
  pack_convw_k<<<12288, 256, 0, stream>>>(conv2_w, cw2);
  pack_scale_k<<<4096, 256, 0, stream>>>(Wq, wqkv,             1024*1024, 0.125f*1.4426950408889634f);
  pack_scale_k<<<4096, 256, 0, stream>>>(Wk, wqkv + (1u<<20),  1024*1024, 1.f);
  pack_scale_k<<<4096, 256, 0, stream>>>(Wv, wqkv + (2u<<20),  1024*1024, 1.f);
  pack_scale_k<<<4096, 256, 0, stream>>>(Wo, wo,               1024*1024, 1.f);
  pack_scale_k<<<16384, 256, 0, stream>>>(W1, w1p, 4096*1024, 1.f);
  pack_scale_k<<<16384, 256, 0, stream>>>(W2, w2p, 4096*1024, 1.f);
  pad_x_k<<<NB*SP, 256, 0, stream>>>(x, xpad);

  // conv1 -> relu -> LN1 (padded bf16 for conv2)
  conv_gemm<<<dim3(32,8), 512, 0, stream>>>(xpad, cw1, pre);
  ln_k<0><<<NB*SP, 256, 0, stream>>>(pre, conv1_b, ln1_g, ln1_b, nullptr, nullptr, hpad);
  // conv2 -> relu -> LN2 -> +x => inputs (f32)
  conv_gemm<<<dim3(32,8), 512, 0, stream>>>(hpad, cw2, pre);
  ln_k<1><<<NTOK, 256, 0, stream>>>(pre, conv2_b, ln2_g, ln2_b, x, inputs, nullptr);
  // lnA -> xn (bf16)
  ln_k<2><<<NTOK, 256, 0, stream>>>(inputs, nullptr, lnA_g, lnA_b, nullptr, nullptr, xnb);
  // fused QKV projection (8-phase 256^2)
  gemm8<16><<<dim3(16,12), 512, 0, stream>>>(xnb, wqkv, 3072, 1024, nullptr, nullptr, qkvb);
  // flash attention
  attn_k<<<512, 256, 0, stream>>>(qkvb, ctxb);
  // out = ctx @ Wo^T + inputs
  gemm_wo<<<dim3(32,8), 512, 0, stream>>>(ctxb, wo, inputs, out);
  // lnF -> bf16
  ln_k<2><<<NTOK, 256, 0, stream>>>(out, nullptr, lnF_g, lnF_b, nullptr, nullptr, lnfb);
  // inter = relu(lnF @ W1^T + b1) (8-phase 256^2)
  gemm8<19><<<dim3(16,16), 512, 0, stream>>>(lnfb, w1p, 4096, 1024, b1, nullptr, interb);
  // final = (inter @ W2^T + b2)*mask + out
  gemm_f2<<<dim3(32,8), 512, 0, stream>>>(interb, w2p, b2, ffnmask, out);
}

// Round 8
// 318.723 us; speedup vs baseline: 1.4052x; 1.2568x over previous
//
#include <hip/hip_runtime.h>
#include <hip/hip_bf16.h>
#include <cstdint>
#include <cstddef>

// TransformerEncoderLayer: B=2 S=2048 D=1024 H=16 DH=64 DFF=4096, fp32 in/out.
// Round 7: (a) attn reverted to r3-exact (74us measured; r6's exp2/defer-max/
// v_perm bundle regressed it). (b) 8-phase abandoned (2 failed ports); QKV/FFN1
// back to 2-phase 64KB/2-blocks-per-CU. (c) NEW: grid-256 GEMMs (convs, Wo,
// FFN2) use 3-buffer rotation + counted vmcnt(4) + raw s_barrier -> no
// vmcnt(0) drain per K-step at 1 block/CU.

#define SB 2048
#define DD 1024
#define NB 2
#define NH 16
#define DFF_ 4096
#define NTOK (NB*SB)   // 4096
#define SP (SB+2)      // 2050 (padded rows for conv halo)

typedef unsigned short u16;
typedef unsigned int u32;
typedef float f32x4 __attribute__((ext_vector_type(4)));
typedef float f32x16 __attribute__((ext_vector_type(16)));
typedef short s16x8 __attribute__((ext_vector_type(8)));
typedef int s32x2 __attribute__((ext_vector_type(2)));
typedef u32 u32x4 __attribute__((ext_vector_type(4)));

__device__ __forceinline__ u16 f2b(float f){
  uint32_t u = __builtin_bit_cast(uint32_t, f);
  return (u16)((u + 0x7fffu + ((u >> 16) & 1u)) >> 16);  // RNE
}
__device__ __forceinline__ u32 pkbf(float lo, float hi){
  u32 r;
  asm("v_cvt_pk_bf16_f32 %0, %1, %2" : "=v"(r) : "v"(lo), "v"(hi));
  return r;
}

// ---------------- workspace layout (bytes) ----------------
constexpr size_t OFF_CW1   = 0;                                     // 3x1024x1024 bf16
constexpr size_t OFF_CW2   = OFF_CW1 + 3ull*1024*1024*2;
constexpr size_t OFF_WQKV  = OFF_CW2 + 3ull*1024*1024*2;            // 3072x1024 bf16 (q scaled 1/8)
constexpr size_t OFF_WO    = OFF_WQKV + 3072ull*1024*2;
constexpr size_t OFF_W1    = OFF_WO + 1024ull*1024*2;
constexpr size_t OFF_W2    = OFF_W1 + 4096ull*1024*2;
constexpr size_t OFF_PRE   = OFF_W2 + 4096ull*1024*2;               // f32 4096x1024
constexpr size_t OFF_QKVB  = OFF_PRE + (size_t)NTOK*1024*4;         // bf16 4096x3072
constexpr size_t OFF_INTER = OFF_PRE;                               // alias: bf16 4096x4096
constexpr size_t OFF_XPAD  = OFF_QKVB + (size_t)NTOK*3072*2;        // bf16 2x2050x1024
constexpr size_t OFF_LNF   = OFF_XPAD;                              // alias
constexpr size_t OFF_HPAD  = OFF_XPAD + (size_t)NB*SP*1024*2;       // bf16 2x2050x1024
constexpr size_t OFF_CTX   = OFF_HPAD;                              // alias
constexpr size_t OFF_INPUTS= OFF_HPAD + (size_t)NB*SP*1024*2;       // f32 4096x1024
constexpr size_t OFF_XN    = OFF_INPUTS + (size_t)NTOK*1024*4;      // bf16 4096x1024

// ---------------- pack kernels ----------------
__global__ void pack_scale_k(const float* __restrict__ in, u16* __restrict__ out, int n, float scale){
  int i = blockIdx.x*256 + threadIdx.x;
  if (i < n) out[i] = f2b(in[i]*scale);
}

// w[o][i][t] (D,D,3) -> out[t][o][i] bf16
__global__ void pack_convw_k(const float* __restrict__ w, u16* __restrict__ out){
  int i = blockIdx.x*256 + threadIdx.x;   // over 3*1024*1024
  int t = i >> 20;
  int rem = i & 1048575;
  int o = rem >> 10;
  int c = rem & 1023;
  out[i] = f2b(w[o*3072 + c*3 + t]);
}

// x f32 (B,S,D) -> xpad bf16 (B,S+2,D), zero halo rows
__global__ void pad_x_k(const float* __restrict__ x, u16* __restrict__ xp){
  int row = blockIdx.x;  // 0..NB*SP-1
  int tid = threadIdx.x;
  int b = row / SP, s = row - b*SP;
  ushort4 st;
  if (s == 0 || s == SP-1){ st.x=0; st.y=0; st.z=0; st.w=0; }
  else {
    float4 v = ((const float4*)(x + ((size_t)b*SB + s-1)*DD))[tid];
    st.x=f2b(v.x); st.y=f2b(v.y); st.z=f2b(v.z); st.w=f2b(v.w);
  }
  ((ushort4*)(xp + (size_t)row*DD))[tid] = st;
}

// ---------------- LayerNorm ----------------
template<int MODE>
__global__ __launch_bounds__(256) void ln_k(const float* __restrict__ in, const float* __restrict__ cb,
    const float* __restrict__ g, const float* __restrict__ be, const float* __restrict__ resid,
    float* __restrict__ outf, u16* __restrict__ outb)
{
  int row = blockIdx.x, tid = threadIdx.x;
  int inrow = row;
  if (MODE == 0){
    int b = row / SP, s = row - b*SP;
    if (s == 0 || s == SP-1){
      ushort4 z; z.x=0; z.y=0; z.z=0; z.w=0;
      ((ushort4*)(outb + (size_t)row*DD))[tid] = z;
      return;
    }
    inrow = b*SB + s - 1;
  }
  float4 v = ((const float4*)(in + (size_t)inrow*DD))[tid];
  if (MODE <= 1){
    float4 c = ((const float4*)cb)[tid];
    v.x = fmaxf(v.x + c.x, 0.f);
    v.y = fmaxf(v.y + c.y, 0.f);
    v.z = fmaxf(v.z + c.z, 0.f);
    v.w = fmaxf(v.w + c.w, 0.f);
  }
  float s1 = v.x+v.y+v.z+v.w;
  float s2 = v.x*v.x + v.y*v.y + v.z*v.z + v.w*v.w;
  #pragma unroll
  for (int d=32; d>=1; d>>=1){ s1 += __shfl_down(s1, d); s2 += __shfl_down(s2, d); }
  __shared__ float red[8];
  int wid = tid >> 6, lane = tid & 63;
  if (lane==0){ red[wid] = s1; red[4+wid] = s2; }
  __syncthreads();
  s1 = red[0]+red[1]+red[2]+red[3];
  s2 = red[4]+red[5]+red[6]+red[7];
  float mu = s1 * (1.f/DD);
  float var = s2 * (1.f/DD) - mu*mu;
  float rs = rsqrtf(var + 1e-6f);
  float4 gg = ((const float4*)g)[tid];
  float4 bb = ((const float4*)be)[tid];
  float o0 = (v.x-mu)*rs*gg.x + bb.x;
  float o1 = (v.y-mu)*rs*gg.y + bb.y;
  float o2 = (v.z-mu)*rs*gg.z + bb.z;
  float o3 = (v.w-mu)*rs*gg.w + bb.w;
  if (MODE == 1){
    float4 rr = ((const float4*)(resid + (size_t)inrow*DD))[tid];
    float4 o; o.x=o0+rr.x; o.y=o1+rr.y; o.z=o2+rr.z; o.w=o3+rr.w;
    ((float4*)(outf + (size_t)inrow*DD))[tid] = o;
  } else {
    ushort4 st; st.x=f2b(o0); st.y=f2b(o1); st.z=f2b(o2); st.w=f2b(o3);
    ((ushort4*)(outb + (size_t)row*DD))[tid] = st;
  }
}

// ---------------- shared GEMM helpers ----------------
__device__ __forceinline__ void glds16(const u16* g, u16* l){
  __builtin_amdgcn_global_load_lds((const __attribute__((address_space(1))) void*)g,
                                   (__attribute__((address_space(3))) void*)l, 16, 0, 0);
}

// stage a [128 rows][64 cols] bf16 tile (16KB) with 512 threads, XOR-swizzled
// via pre-swizzled GLOBAL source (global_load_lds writes linearly).
__device__ __forceinline__ void stage_tile8(const u16* __restrict__ src, int strideK, u16* lds, int wid, int lane){
  #pragma unroll
  for (int i=0;i<2;i++){
    int chunk = (wid<<1) + i;            // 16 chunks x 1KB
    int p = (chunk<<10) + (lane<<4);     // linear LDS byte this lane fills
    int row = p >> 7;
    int clg = (p & 127) ^ ((row & 7) << 4);
    glds16(src + (size_t)row*strideK + (clg>>1), lds + (chunk<<9));
  }
}

__device__ __forceinline__ s16x8 ldsrd(const u16* slot, int r, int ks, int hi){
  int off = (r<<7) + (((ks<<6)+(hi<<4)) ^ ((r&7)<<4));
  return *(const s16x8*)((const char*)slot + off);
}

__device__ __forceinline__ void kstep_mfma8(const u16* As, const u16* Bs, int wr, int wc, int lr, int hi, f32x4 acc[4][2]){
  s16x8 af[2][4], bf[2][2];
  #pragma unroll
  for (int ks=0; ks<2; ++ks){
    #pragma unroll
    for (int m=0;m<4;m++) af[ks][m] = ldsrd(As, (wr<<6)+(m<<4)+lr, ks, hi);
    #pragma unroll
    for (int n=0;n<2;n++) bf[ks][n] = ldsrd(Bs, (wc<<5)+(n<<4)+lr, ks, hi);
  }
  #pragma unroll
  for (int ks=0;ks<2;++ks)
    #pragma unroll
    for (int m=0;m<4;m++)
      #pragma unroll
      for (int n=0;n<2;n++)
        acc[m][n] = __builtin_amdgcn_mfma_f32_16x16x32_bf16(af[ks][m], bf[ks][n], acc[m][n], 0,0,0);
}

// ---------------- 2-phase 128x128 GEMM (QKV, FFN1: >=512-block grids) -------
// EPI: 1 bias, 2 relu, 16 bf16-out (else f32)
template<int EPI>
__global__ __launch_bounds__(512,4) void gemm2(const u16* __restrict__ A, const u16* __restrict__ Bm,
    int N, int K, const float* __restrict__ bias, float* __restrict__ Cf, u16* __restrict__ Cb)
{
  __shared__ __attribute__((aligned(16))) u16 As[2][128*64];
  __shared__ __attribute__((aligned(16))) u16 Bs[2][128*64];
  int tid=threadIdx.x, wid=tid>>6, lane=tid&63, lr=lane&15, hi=lane>>4;
  int wr=wid>>2, wc=wid&3;
  int m0=blockIdx.x<<7, n0=blockIdx.y<<7;
  f32x4 acc[4][2] = {};
  const u16* Ab = A + (size_t)m0*K;
  const u16* Bb = Bm + (size_t)n0*K;
  int nk = K >> 6;
  stage_tile8(Ab, K, As[0], wid, lane);
  stage_tile8(Bb, K, Bs[0], wid, lane);
  __syncthreads();
  int cur = 0;
  for (int kt=0; kt<nk; ++kt){
    if (kt+1 < nk){
      stage_tile8(Ab + ((kt+1)<<6), K, As[cur^1], wid, lane);
      stage_tile8(Bb + ((kt+1)<<6), K, Bs[cur^1], wid, lane);
    }
    kstep_mfma8(As[cur], Bs[cur], wr, wc, lr, hi, acc);
    __syncthreads();
    cur ^= 1;
  }
  #pragma unroll
  for (int m=0;m<4;m++)
    #pragma unroll
    for (int r=0;r<4;r++){
      int row = m0 + (wr<<6) + (m<<4) + (hi<<2) + r;
      #pragma unroll
      for (int n=0;n<2;n++){
        int col = n0 + (wc<<5) + (n<<4) + lr;
        float v = acc[m][n][r];
        if (EPI&1) v += bias[col];
        if (EPI&2) v = fmaxf(v, 0.f);
        if (EPI&16) Cb[(size_t)row*N + col] = f2b(v);
        else Cf[(size_t)row*N + col] = v;
      }
    }
}

// ---------------- 3-buffer counted-vmcnt 128x128 GEMM (grid-256 kernels) ----
// Per iter: {ds_read(t); stage(t+2) [4 glds]; vmcnt(4); MFMA(t); s_barrier}.
// No vmcnt(0) drain in steady state. Buffer overwrite race-free: stage(t+2)
// targets the buffer read at t-1, whose reads retired (lgkmcnt before MFMA)
// before each wave's barrier arrival. Epilogue iters drain with vmcnt(0).
// EPI: 1 bias, 4 +resid, 8 *rowmask
template<int EPI>
__global__ __launch_bounds__(512,2) void gemm3(const u16* __restrict__ A, const u16* __restrict__ Bm,
    int N, int K, const float* __restrict__ bias, const float* __restrict__ resid,
    const float* __restrict__ rowmask, float* __restrict__ Cf)
{
  __shared__ __attribute__((aligned(16))) u16 As[3][128*64];
  __shared__ __attribute__((aligned(16))) u16 Bs[3][128*64];
  int tid=threadIdx.x, wid=tid>>6, lane=tid&63, lr=lane&15, hi=lane>>4;
  int wr=wid>>2, wc=wid&3;
  int m0=blockIdx.x<<7, n0=blockIdx.y<<7;
  f32x4 acc[4][2] = {};
  const u16* Ab = A + (size_t)m0*K;
  const u16* Bb = Bm + (size_t)n0*K;
  int NT = K >> 6;
  stage_tile8(Ab,      K, As[0], wid, lane);
  stage_tile8(Bb,      K, Bs[0], wid, lane);
  stage_tile8(Ab + 64, K, As[1], wid, lane);
  stage_tile8(Bb + 64, K, Bs[1], wid, lane);
  asm volatile("s_waitcnt vmcnt(4)" ::: "memory");
  __builtin_amdgcn_s_barrier();
  const u16 *pa0=As[0], *pa1=As[1], *pa2=As[2];
  const u16 *pb0=Bs[0], *pb1=Bs[1], *pb2=Bs[2];
  for (int t=0; t<NT; ++t){
    s16x8 af[2][4], bf[2][2];
    #pragma unroll
    for (int ks=0; ks<2; ++ks){
      #pragma unroll
      for (int m=0;m<4;m++) af[ks][m] = ldsrd(pa0, (wr<<6)+(m<<4)+lr, ks, hi);
      #pragma unroll
      for (int n=0;n<2;n++) bf[ks][n] = ldsrd(pb0, (wc<<5)+(n<<4)+lr, ks, hi);
    }
    if (t+2 < NT){
      stage_tile8(Ab + ((t+2)<<6), K, (u16*)pa2, wid, lane);
      stage_tile8(Bb + ((t+2)<<6), K, (u16*)pb2, wid, lane);
      asm volatile("s_waitcnt vmcnt(4)" ::: "memory");   // stage(t+1) landed
    } else {
      asm volatile("s_waitcnt vmcnt(0)" ::: "memory");   // tail drain
    }
    #pragma unroll
    for (int ks=0;ks<2;++ks)
      #pragma unroll
      for (int m=0;m<4;m++)
        #pragma unroll
        for (int n=0;n<2;n++)
          acc[m][n] = __builtin_amdgcn_mfma_f32_16x16x32_bf16(af[ks][m], bf[ks][n], acc[m][n], 0,0,0);
    __builtin_amdgcn_s_barrier();
    const u16* ta=pa0; pa0=pa1; pa1=pa2; pa2=ta;
    const u16* tb=pb0; pb0=pb1; pb1=pb2; pb2=tb;
  }
  #pragma unroll
  for (int m=0;m<4;m++)
    #pragma unroll
    for (int r=0;r<4;r++){
      int row = m0 + (wr<<6) + (m<<4) + (hi<<2) + r;
      float rm = (EPI&8) ? rowmask[row] : 1.f;
      #pragma unroll
      for (int n=0;n<2;n++){
        int col = n0 + (wc<<5) + (n<<4) + lr;
        float v = acc[m][n][r];
        if (EPI&1) v += bias[col];
        if (EPI&8) v *= rm;
        if (EPI&4) v += resid[(size_t)row*N + col];
        Cf[(size_t)row*N + col] = v;
      }
    }
}

// conv as GEMM over padded activations, taps flattened, 3-buffer counted-vmcnt
__global__ __launch_bounds__(512,2) void conv3(const u16* __restrict__ xp, const u16* __restrict__ W3,
    float* __restrict__ Cf)
{
  __shared__ __attribute__((aligned(16))) u16 As[3][128*64];
  __shared__ __attribute__((aligned(16))) u16 Bs[3][128*64];
  int tid=threadIdx.x, wid=tid>>6, lane=tid&63, lr=lane&15, hi=lane>>4;
  int wr=wid>>2, wc=wid&3;
  int m0=blockIdx.x<<7, n0=blockIdx.y<<7;
  int bb = m0 >> 11, ss = m0 & 2047;
  f32x4 acc[4][2] = {};
  const u16* ab0 = xp + ((size_t)bb*SP + ss)*DD;
  const u16* bb0 = W3 + ((size_t)n0<<10);
  const int NT = 48;   // tap = idx>>4, kt = idx&15
#define CSRCA(idx) (ab0 + (size_t)((idx)>>4)*DD + (((idx)&15)<<6))
#define CSRCB(idx) (bb0 + ((size_t)((idx)>>4)<<20) + (((idx)&15)<<6))
  stage_tile8(CSRCA(0), DD, As[0], wid, lane);
  stage_tile8(CSRCB(0), DD, Bs[0], wid, lane);
  stage_tile8(CSRCA(1), DD, As[1], wid, lane);
  stage_tile8(CSRCB(1), DD, Bs[1], wid, lane);
  asm volatile("s_waitcnt vmcnt(4)" ::: "memory");
  __builtin_amdgcn_s_barrier();
  const u16 *pa0=As[0], *pa1=As[1], *pa2=As[2];
  const u16 *pb0=Bs[0], *pb1=Bs[1], *pb2=Bs[2];
  for (int t=0; t<NT; ++t){
    s16x8 af[2][4], bf[2][2];
    #pragma unroll
    for (int ks=0; ks<2; ++ks){
      #pragma unroll
      for (int m=0;m<4;m++) af[ks][m] = ldsrd(pa0, (wr<<6)+(m<<4)+lr, ks, hi);
      #pragma unroll
      for (int n=0;n<2;n++) bf[ks][n] = ldsrd(pb0, (wc<<5)+(n<<4)+lr, ks, hi);
    }
    if (t+2 < NT){
      stage_tile8(CSRCA(t+2), DD, (u16*)pa2, wid, lane);
      stage_tile8(CSRCB(t+2), DD, (u16*)pb2, wid, lane);
      asm volatile("s_waitcnt vmcnt(4)" ::: "memory");
    } else {
      asm volatile("s_waitcnt vmcnt(0)" ::: "memory");
    }
    #pragma unroll
    for (int ks=0;ks<2;++ks)
      #pragma unroll
      for (int m=0;m<4;m++)
        #pragma unroll
        for (int n=0;n<2;n++)
          acc[m][n] = __builtin_amdgcn_mfma_f32_16x16x32_bf16(af[ks][m], bf[ks][n], acc[m][n], 0,0,0);
    __builtin_amdgcn_s_barrier();
    const u16* ta=pa0; pa0=pa1; pa1=pa2; pa2=ta;
    const u16* tb=pb0; pb0=pb1; pb1=pb2; pb2=tb;
  }
#undef CSRCA
#undef CSRCB
  #pragma unroll
  for (int m=0;m<4;m++)
    #pragma unroll
    for (int r=0;r<4;r++){
      int row = m0 + (wr<<6) + (m<<4) + (hi<<2) + r;
      #pragma unroll
      for (int n=0;n<2;n++){
        int col = n0 + (wc<<5) + (n<<4) + lr;
        Cf[(size_t)row*DD + col] = acc[m][n][r];
      }
    }
}

// ---------------- flash attention (r3-exact revert) ----------------
// qkv: [NTOK][3072] bf16 = [q(1024) k(1024) v(1024)], q pre-scaled 1/8.
// Grid 512 blocks; hb=bid&31 -> (h,b), qt=bid>>5 (XCD locality). 4 waves,
// wave owns 32 q rows. KV tile 64 keys, 32 iters.
// QK^T: S^T[key][q] = mfma32(K, Q)  -> col=lane&31=q (lane-local softmax).
// PV:   O^T[d][q]   = mfma32(V^T, P^T) -> col=q again (lane-local rescale).
// P^T B-frags built in-register: v_cvt_pk_bf16_f32 + permlane32_swap.
__global__ __launch_bounds__(256,2) void attn_k(const u16* __restrict__ qkv, u16* __restrict__ ctx)
{
  __shared__ __attribute__((aligned(16))) u16 Ks[2][64*64];  // [key][d], 128B rows, swz
  __shared__ __attribute__((aligned(16))) u16 Vt[64*64];     // [d][key], 128B rows, swz
  int tid=threadIdx.x, wid=tid>>6, lane=tid&63, ql=lane&31, hl=lane>>5;
  int bid = blockIdx.x;
  int hb = bid & 31, qt = bid >> 5;
  int h = hb & 15, b = hb >> 4;
  int q0 = (qt<<7) + (wid<<5);
  size_t kbase = ((size_t)b*SB)*3072 + 1024 + (h<<6);
  size_t vbase = kbase + 1024;

  // Q B-frags: bq[dc] = Q[q0+ql][16dc+8hl .. +7]
  s16x8 bq[4];
  {
    size_t qrow = ((size_t)b*SB + q0 + ql)*3072 + (h<<6);
    #pragma unroll
    for (int dc=0; dc<4; ++dc) bq[dc] = *(const s16x8*)(qkv + qrow + (dc<<4) + (hl<<3));
  }

  int kp = tid & 31, dgrp = tid >> 5;   // V loader: keys 2kp,2kp+1, d 8dgrp..+7

  // prologue: stage K tile 0, load V tile 0
  #pragma unroll
  for (int i=0;i<2;i++){
    int chunk = (wid<<1)+i;
    int p = (chunk<<10) + (lane<<4);
    int row = p>>7;
    int colb = (p&127) ^ ((row&7)<<4);
    glds16(qkv + kbase + (size_t)row*3072 + (colb>>1), Ks[0] + (chunk<<9));
  }
  s16x8 v0 = *(const s16x8*)(qkv + vbase + (size_t)(2*kp)*3072 + (dgrp<<3));
  s16x8 v1 = *(const s16x8*)(qkv + vbase + (size_t)(2*kp+1)*3072 + (dgrp<<3));

  float m_r = -1e30f, l_r = 0.f;
  f32x16 acc[2] = {};
  int cur = 0;
  for (int kt=0; kt<32; ++kt){
    __syncthreads();                 // prev Vt reads done; Ks[cur] staged
    // V transpose into Vt[d][key] (u32 key-pairs, 2 lanes/bank)
    #pragma unroll
    for (int i=0;i<8;i++){
      int d = (dgrp<<3)+i;
      u32 val = ((u32)(u16)v0[i]) | (((u32)(u16)v1[i])<<16);
      *(u32*)((char*)Vt + (d<<7) + ((kp<<2) ^ ((d&7)<<4))) = val;
    }
    __syncthreads();                 // Vt ready
    if (kt+1 < 32){                  // prefetch next tile
      int k0n = (kt+1)<<6;
      #pragma unroll
      for (int i=0;i<2;i++){
        int chunk = (wid<<1)+i;
        int p = (chunk<<10) + (lane<<4);
        int row = p>>7;
        int colb = (p&127) ^ ((row&7)<<4);
        glds16(qkv + kbase + (size_t)(k0n+row)*3072 + (colb>>1), Ks[cur^1] + (chunk<<9));
      }
      v0 = *(const s16x8*)(qkv + vbase + (size_t)(k0n + 2*kp)*3072 + (dgrp<<3));
      v1 = *(const s16x8*)(qkv + vbase + (size_t)(k0n + 2*kp+1)*3072 + (dgrp<<3));
    }
    // QK^T: s0 = keys 0..31 (local), s1 = keys 32..63; col=q=ql
    const char* Kb = (const char*)Ks[cur];
    f32x16 s0 = {}, s1 = {};
    #pragma unroll
    for (int dc=0; dc<4; ++dc){
      int cb = ((dc<<4) + (hl<<3)) << 1;
      {
        int row = ql;
        s16x8 ka = *(const s16x8*)(Kb + (row<<7) + (cb ^ ((row&7)<<4)));
        s0 = __builtin_amdgcn_mfma_f32_32x32x16_bf16(ka, bq[dc], s0, 0,0,0);
      }
      {
        int row = 32+ql;
        s16x8 ka = *(const s16x8*)(Kb + (row<<7) + (cb ^ ((row&7)<<4)));
        s1 = __builtin_amdgcn_mfma_f32_32x32x16_bf16(ka, bq[dc], s1, 0,0,0);
      }
    }
    // online softmax (q lane-local; only cross-op is lane^32)
    float mt = s0[0];
    #pragma unroll
    for (int r=1;r<16;r++) mt = fmaxf(mt, s0[r]);
    #pragma unroll
    for (int r=0;r<16;r++) mt = fmaxf(mt, s1[r]);
    mt = fmaxf(mt, __shfl_xor(mt, 32));
    float mn = fmaxf(m_r, mt);
    float al = __expf(m_r - mn);
    m_r = mn;
    float sm = 0.f;
    #pragma unroll
    for (int r=0;r<16;r++){ s0[r] = __expf(s0[r]-mn); sm += s0[r]; }
    #pragma unroll
    for (int r=0;r<16;r++){ s1[r] = __expf(s1[r]-mn); sm += s1[r]; }
    sm += __shfl_xor(sm, 32);
    l_r = l_r*al + sm;
    acc[0] = acc[0]*al;
    acc[1] = acc[1]*al;
    // P^T B-frags: chunk c keys 16c+8hl+j; reg f = keys (2f,2f+1) packed
    s16x8 pb[4];
    #pragma unroll
    for (int c=0;c<4;c++){
      u32x4 fr;
      #pragma unroll
      for (int bp=0; bp<2; ++bp){
        int ba = 8*(c&1);
        float alo, ahi, blo, bhi;
        if (c>>1){ alo=s1[ba+2*bp]; ahi=s1[ba+2*bp+1]; blo=s1[ba+4+2*bp]; bhi=s1[ba+4+2*bp+1]; }
        else     { alo=s0[ba+2*bp]; ahi=s0[ba+2*bp+1]; blo=s0[ba+4+2*bp]; bhi=s0[ba+4+2*bp+1]; }
        u32 A = pkbf(alo, ahi);
        u32 B = pkbf(blo, bhi);
        s32x2 swp = __builtin_amdgcn_permlane32_swap((int)A, (int)B, false, false);
        fr[bp]   = (u32)swp[0];
        fr[bp+2] = (u32)swp[1];
      }
      pb[c] = __builtin_bit_cast(s16x8, fr);
    }
    // PV: acc[dh] (rows d=32dh+.., col=q) += mfma32(V^T-frag, P^T-frag)
    #pragma unroll
    for (int dh=0; dh<2; ++dh){
      #pragma unroll
      for (int c=0;c<4;c++){
        int d = (dh<<5) + ql;
        s16x8 vf = *(const s16x8*)((const char*)Vt + (d<<7) + ((((c<<5)+(hl<<4))) ^ ((d&7)<<4)));
        acc[dh] = __builtin_amdgcn_mfma_f32_32x32x16_bf16(vf, pb[c], acc[dh], 0,0,0);
      }
    }
    cur ^= 1;
  }
  __syncthreads();   // all waves done with Ks before reusing it as Os
  // epilogue: O^T[d][q] -> transpose via per-wave LDS region -> coalesced ctx
  float inv = 1.f / l_r;
  u16* Os = (u16*)Ks[0] + (wid<<11);    // 4KB per wave: [32 q][64 d], swz
  #pragma unroll
  for (int dh=0; dh<2; ++dh)
    #pragma unroll
    for (int a=0;a<4;a++)
      #pragma unroll
      for (int bp=0;bp<2;bp++){
        u32 w = pkbf(acc[dh][4*a+2*bp]*inv, acc[dh][4*a+2*bp+1]*inv);
        int d2 = (dh<<5) + (a<<3) + (hl<<2) + (bp<<1);
        *(u32*)((char*)Os + (ql<<7) + (((d2<<1)) ^ ((ql&7)<<4))) = w;
      }
  // wave-internal: DS ops in-order per wave; read back rows, store coalesced
  int rw = lane>>1, half = lane&1;
  size_t gb = ((size_t)b*SB + q0 + rw)*DD + (h<<6) + (half<<5);
  #pragma unroll
  for (int j=0;j<4;j++){
    s16x8 o = *(const s16x8*)((const char*)Os + (rw<<7) + ((((half<<6)+(j<<4))) ^ ((rw&7)<<4)));
    *(s16x8*)(ctx + gb + (j<<3)) = o;
  }
}

// ---------------- launch ----------------
extern "C" void kernel_launch(void* const* d_in, const int* in_sizes, int n_in,
                              void* d_out, int out_size, void* d_ws, size_t ws_size,
                              hipStream_t stream)
{
  (void)in_sizes; (void)n_in; (void)out_size; (void)ws_size;
  const float* x       = (const float*)d_in[0];
  const float* ffnmask = (const float*)d_in[2];
  const float* conv1_w = (const float*)d_in[3];
  const float* conv1_b = (const float*)d_in[4];
  const float* ln1_g   = (const float*)d_in[5];
  const float* ln1_b   = (const float*)d_in[6];
  const float* conv2_w = (const float*)d_in[7];
  const float* conv2_b = (const float*)d_in[8];
  const float* ln2_g   = (const float*)d_in[9];
  const float* ln2_b   = (const float*)d_in[10];
  const float* lnA_g   = (const float*)d_in[11];
  const float* lnA_b   = (const float*)d_in[12];
  const float* Wq      = (const float*)d_in[13];
  const float* Wk      = (const float*)d_in[14];
  const float* Wv      = (const float*)d_in[15];
  const float* Wo      = (const float*)d_in[16];
  const float* lnF_g   = (const float*)d_in[17];
  const float* lnF_b   = (const float*)d_in[18];
  const float* W1      = (const float*)d_in[19];
  const float* b1      = (const float*)d_in[20];
  const float* W2      = (const float*)d_in[21];
  const float* b2      = (const float*)d_in[22];
  float* out = (float*)d_out;
  char* ws = (char*)d_ws;
  u16*  cw1    = (u16*)(ws + OFF_CW1);
  u16*  cw2    = (u16*)(ws + OFF_CW2);
  u16*  wqkv   = (u16*)(ws + OFF_WQKV);
  u16*  wo     = (u16*)(ws + OFF_WO);
  u16*  w1p    = (u16*)(ws + OFF_W1);
  u16*  w2p    = (u16*)(ws + OFF_W2);
  float* pre   = (float*)(ws + OFF_PRE);
  u16*  qkvb   = (u16*)(ws + OFF_QKVB);
  u16*  interb = (u16*)(ws + OFF_INTER);
  u16*  xpad   = (u16*)(ws + OFF_XPAD);
  u16*  lnfb   = (u16*)(ws + OFF_LNF);
  u16*  hpad   = (u16*)(ws + OFF_HPAD);
  u16*  ctxb   = (u16*)(ws + OFF_CTX);
  float* inputs= (float*)(ws + OFF_INPUTS);
  u16*  xnb    = (u16*)(ws + OFF_XN);

  // weight packs (bf16); q-scale 1/sqrt(64) folded into Wq
  pack_convw_k<<<12288, 256, 0, stream>>>(conv1_w, cw1);
  pack_convw_k<<<12288, 256, 0, stream>>>(conv2_w, cw2);
  pack_scale_k<<<4096, 256, 0, stream>>>(Wq, wqkv,             1024*1024, 0.125f);
  pack_scale_k<<<4096, 256, 0, stream>>>(Wk, wqkv + (1u<<20),  1024*1024, 1.f);
  pack_scale_k<<<4096, 256, 0, stream>>>(Wv, wqkv + (2u<<20),  1024*1024, 1.f);
  pack_scale_k<<<4096, 256, 0, stream>>>(Wo, wo,               1024*1024, 1.f);
  pack_scale_k<<<16384, 256, 0, stream>>>(W1, w1p, 4096*1024, 1.f);
  pack_scale_k<<<16384, 256, 0, stream>>>(W2, w2p, 4096*1024, 1.f);
  pad_x_k<<<NB*SP, 256, 0, stream>>>(x, xpad);

  // conv1 -> relu -> LN1 (padded bf16 for conv2)
  conv3<<<dim3(32,8), 512, 0, stream>>>(xpad, cw1, pre);
  ln_k<0><<<NB*SP, 256, 0, stream>>>(pre, conv1_b, ln1_g, ln1_b, nullptr, nullptr, hpad);
  // conv2 -> relu -> LN2 -> +x => inputs (f32)
  conv3<<<dim3(32,8), 512, 0, stream>>>(hpad, cw2, pre);
  ln_k<1><<<NTOK, 256, 0, stream>>>(pre, conv2_b, ln2_g, ln2_b, x, inputs, nullptr);
  // lnA -> xn (bf16)
  ln_k<2><<<NTOK, 256, 0, stream>>>(inputs, nullptr, lnA_g, lnA_b, nullptr, nullptr, xnb);
  // fused QKV projection (2-phase, 768 blocks)
  gemm2<16><<<dim3(32,24), 512, 0, stream>>>(xnb, wqkv, 3072, 1024, nullptr, nullptr, qkvb);
  // flash attention
  attn_k<<<512, 256, 0, stream>>>(qkvb, ctxb);
  // out = ctx @ Wo^T + inputs (3-buffer counted)
  gemm3<4><<<dim3(32,8), 512, 0, stream>>>(ctxb, wo, 1024, 1024, nullptr, inputs, nullptr, out);
  // lnF -> bf16
  ln_k<2><<<NTOK, 256, 0, stream>>>(out, nullptr, lnF_g, lnF_b, nullptr, nullptr, lnfb);
  // inter = relu(lnF @ W1^T + b1) (2-phase, 1024 blocks)
  gemm2<19><<<dim3(32,32), 512, 0, stream>>>(lnfb, w1p, 4096, 1024, b1, nullptr, interb);
  // final = (inter @ W2^T + b2)*mask + out (3-buffer counted, in-place resid)
  gemm3<13><<<dim3(32,8), 512, 0, stream>>>(interb, w2p, 1024, 4096, b2, out, ffnmask, out);
}